// Round 7
// baseline (476.734 us; speedup 1.0000x reference)
//
#include <hip/hip_runtime.h>

constexpr int NN = 100000;   // nodes
constexpr int NE = 1600000;  // edges
constexpr int DD = 64;       // channels
constexpr int NG = 256;      // graphs

constexpr int BKT_SHIFT = 8;                   // 256 nodes per bucket
constexpr int NBKT = (NN + 255) >> BKT_SHIFT;  // 391 buckets
constexpr int EPB = 4096;                      // edges per block (build kernels)
constexpr int NEB = (NE + EPB - 1) / EPB;      // 391 blocks

// ---------------------------------------------------------------------------
// bf16 helpers (manual, RNE)
// ---------------------------------------------------------------------------
__device__ __forceinline__ float b2f(unsigned short u) {
    union { unsigned int u; float f; } c;
    c.u = ((unsigned int)u) << 16;
    return c.f;
}
__device__ __forceinline__ unsigned short f2b(float f) {
    union { float f; unsigned int u; } c;
    c.f = f;
    unsigned int u = c.u + 0x7fff + ((c.u >> 16) & 1);
    return (unsigned short)(u >> 16);
}

// ---------------------------------------------------------------------------
// CSR build, two-level counting sort (unchanged).
// ---------------------------------------------------------------------------
__global__ __launch_bounds__(256) void bhist_k(const int* __restrict__ ei,
                                               int* __restrict__ gbkt) {
    __shared__ int lc[NBKT];
    for (int i = threadIdx.x; i < NBKT; i += 256) lc[i] = 0;
    __syncthreads();
    int base = blockIdx.x * EPB;
    int end = min(base + EPB, NE);
    for (int e = base + threadIdx.x; e < end; e += 256)
        atomicAdd(&lc[ei[NE + e] >> BKT_SHIFT], 1);
    __syncthreads();
    for (int i = threadIdx.x; i < NBKT; i += 256)
        if (lc[i]) atomicAdd(&gbkt[i], lc[i]);
}

__global__ __launch_bounds__(512) void bscan_k(const int* __restrict__ gbkt,
                                               int* __restrict__ bbase,
                                               int* __restrict__ bcur) {
    __shared__ int sh[512];
    int t = threadIdx.x;
    int v = (t < NBKT) ? gbkt[t] : 0;
    sh[t] = v;
    __syncthreads();
    for (int off = 1; off < 512; off <<= 1) {
        int u = (t >= off) ? sh[t - off] : 0;
        __syncthreads();
        sh[t] += u;
        __syncthreads();
    }
    if (t < NBKT) {
        bbase[t] = sh[t] - v;
        bcur[t] = sh[t] - v;
    }
}

__global__ __launch_bounds__(256) void pscat_k(const int* __restrict__ ei,
                                               int* __restrict__ bcur,
                                               int2* __restrict__ pairs) {
    __shared__ int lc[NBKT];
    __shared__ int gb[NBKT];
    for (int i = threadIdx.x; i < NBKT; i += 256) lc[i] = 0;
    __syncthreads();
    int base = blockIdx.x * EPB;
    int end = min(base + EPB, NE);
    for (int e = base + threadIdx.x; e < end; e += 256)
        atomicAdd(&lc[ei[NE + e] >> BKT_SHIFT], 1);
    __syncthreads();
    for (int i = threadIdx.x; i < NBKT; i += 256) {
        int c = lc[i];
        gb[i] = c ? atomicAdd(&bcur[i], c) : 0;  // reserve exclusive window
    }
    __syncthreads();
    for (int i = threadIdx.x; i < NBKT; i += 256) lc[i] = 0;  // reuse as cursor
    __syncthreads();
    for (int e = base + threadIdx.x; e < end; e += 256) {
        int src = ei[e];
        int dst = ei[NE + e];
        int b = dst >> BKT_SHIFT;
        int pos = gb[b] + atomicAdd(&lc[b], 1);
        pairs[pos] = make_int2(src, dst);
    }
}

__global__ __launch_bounds__(256) void bfill_k(const int2* __restrict__ pairs,
                                               const int* __restrict__ bbase,
                                               const int* __restrict__ gbkt,
                                               int* __restrict__ rowptr,
                                               int* __restrict__ csr_src) {
    __shared__ int ldeg[256];
    __shared__ int sh[256];
    __shared__ int lcur[256];
    int b = blockIdx.x;
    int t = threadIdx.x;
    int nbase = b << BKT_SHIFT;
    int pbeg = bbase[b];
    int pcnt = gbkt[b];
    ldeg[t] = 0;
    __syncthreads();
    for (int i = t; i < pcnt; i += 256)
        atomicAdd(&ldeg[pairs[pbeg + i].y & 255], 1);
    __syncthreads();
    int v = ldeg[t];
    sh[t] = v;
    __syncthreads();
    for (int off = 1; off < 256; off <<= 1) {
        int u = (t >= off) ? sh[t - off] : 0;
        __syncthreads();
        sh[t] += u;
        __syncthreads();
    }
    int lexcl = sh[t] - v;
    int node = nbase + t;
    if (node < NN) {
        rowptr[node] = pbeg + lexcl;
        if (node == NN - 1) rowptr[NN] = pbeg + lexcl + v;
    }
    lcur[t] = lexcl;
    __syncthreads();
    for (int i = t; i < pcnt; i += 256) {
        int2 p = pairs[pbeg + i];
        int pos = atomicAdd(&lcur[p.y & 255], 1);
        csr_src[pbeg + pos] = p.x;
    }
}

// ---------------------------------------------------------------------------
// x (fp32) -> bf16 conversion for the first layer's gather source.
// ---------------------------------------------------------------------------
__global__ __launch_bounds__(256) void xconv_k(const float* __restrict__ x,
                                               unsigned short* __restrict__ xb) {
    int i = blockIdx.x * 256 + threadIdx.x;  // float4 groups, NN*16 total
    if (i < NN * 16) {
        float4 v = reinterpret_cast<const float4*>(x)[i];
        ushort4 o;
        o.x = f2b(v.x); o.y = f2b(v.y); o.z = f2b(v.z); o.w = f2b(v.w);
        reinterpret_cast<ushort4*>(xb)[i] = o;
    }
}

// ---------------------------------------------------------------------------
// Fused GIN layer: gather (bf16 rows, fp32 accumulate) + self term staged
// transposed into LDS zT, then 2-layer MLP as register-blocked GEMM.
// LDS = zT only (17.4 KB) -> high occupancy for the latency-bound gather
// phase; weights read from global (L2-resident 16 KB each).
// Block = 256 threads, 64-node tile; wave w gathers rows 16w..16w+15.
// ---------------------------------------------------------------------------
constexpr int ZS = 68;  // zT leading-dim pad (2-way bank alias: free)

__global__ __launch_bounds__(256, 6) void gin_layer_k(
    const float* __restrict__ hin_f32,        // fp32 self-term (layer 0), else null
    const unsigned short* __restrict__ hinb,  // bf16 h: gather (+self if no fp32)
    const int* __restrict__ rowptr,
    const int* __restrict__ csr_src,
    const float* __restrict__ w1, const float* __restrict__ b1,
    const float* __restrict__ w2, const float* __restrict__ b2,
    unsigned short* __restrict__ houtb, int relu_out) {
    __shared__ float zT[64 * ZS];  // [k][r]
    int tid = threadIdx.x;
    int base = blockIdx.x * 64;
    int lane = tid & 63;
    int wv = tid >> 6;
    int c = lane & 15;    // channel quad 0..15 (4 ch each)
    int grp = lane >> 4;  // edge group 0..3
    const ushort4* hb4 = reinterpret_cast<const ushort4*>(hinb);

    // ---- gather + self term, transposed into zT ----
    for (int rr = 0; rr < 16; ++rr) {
        int r = wv * 16 + rr;
        int node = base + r;
        float4 acc = make_float4(0.f, 0.f, 0.f, 0.f);
        if (node < NN) {
            int beg = rowptr[node];
            int end = rowptr[node + 1];
            for (int i = beg + grp; i < end; i += 4) {
                int s = csr_src[i];
                ushort4 v = hb4[(size_t)s * 16 + c];
                acc.x += b2f(v.x);
                acc.y += b2f(v.y);
                acc.z += b2f(v.z);
                acc.w += b2f(v.w);
            }
        }
#pragma unroll
        for (int off = 32; off >= 16; off >>= 1) {
            acc.x += __shfl_down(acc.x, off, 64);
            acc.y += __shfl_down(acc.y, off, 64);
            acc.z += __shfl_down(acc.z, off, 64);
            acc.w += __shfl_down(acc.w, off, 64);
        }
        if (grp == 0) {  // lanes 0..15 hold the combined row
            float4 self = make_float4(0.f, 0.f, 0.f, 0.f);
            if (node < NN) {
                if (hin_f32) {
                    self = reinterpret_cast<const float4*>(hin_f32)[(size_t)node * 16 + c];
                } else {
                    ushort4 sv = hb4[(size_t)node * 16 + c];
                    self.x = b2f(sv.x); self.y = b2f(sv.y);
                    self.z = b2f(sv.z); self.w = b2f(sv.w);
                }
            }
            zT[(4 * c + 0) * ZS + r] = acc.x + self.x;
            zT[(4 * c + 1) * ZS + r] = acc.y + self.y;
            zT[(4 * c + 2) * ZS + r] = acc.z + self.z;
            zT[(4 * c + 3) * ZS + r] = acc.w + self.w;
        }
    }
    __syncthreads();

    // ---- layer 1: acc = z @ w1 + b1 (weights from global, L2-hot) ----
    int tr = tid & 15;  // rows 4tr..4tr+3
    int tc = tid >> 4;  // cols 4tc..4tc+3
    const float4* w14 = reinterpret_cast<const float4*>(w1);
    float4 bv = reinterpret_cast<const float4*>(b1)[tc];
    float acc[4][4];
#pragma unroll
    for (int rr = 0; rr < 4; ++rr) {
        acc[rr][0] = bv.x; acc[rr][1] = bv.y; acc[rr][2] = bv.z; acc[rr][3] = bv.w;
    }
#pragma unroll 8
    for (int k = 0; k < 64; ++k) {
        float4 zv = *reinterpret_cast<const float4*>(&zT[k * ZS + 4 * tr]);
        float4 wvv = w14[k * 16 + tc];
        const float zr[4] = {zv.x, zv.y, zv.z, zv.w};
        const float wc[4] = {wvv.x, wvv.y, wvv.z, wvv.w};
#pragma unroll
        for (int rr = 0; rr < 4; ++rr)
#pragma unroll
            for (int jj = 0; jj < 4; ++jj)
                acc[rr][jj] = fmaf(zr[rr], wc[jj], acc[rr][jj]);
    }
    __syncthreads();

    // ---- h1 = ReLU(acc) transposed back into zT ----
#pragma unroll
    for (int jj = 0; jj < 4; ++jj) {
        float4 hv;
        hv.x = fmaxf(acc[0][jj], 0.f);
        hv.y = fmaxf(acc[1][jj], 0.f);
        hv.z = fmaxf(acc[2][jj], 0.f);
        hv.w = fmaxf(acc[3][jj], 0.f);
        *reinterpret_cast<float4*>(&zT[(4 * tc + jj) * ZS + 4 * tr]) = hv;
    }
    __syncthreads();

    // ---- layer 2: acc = h1 @ w2 + b2 ----
    const float4* w24 = reinterpret_cast<const float4*>(w2);
    bv = reinterpret_cast<const float4*>(b2)[tc];
#pragma unroll
    for (int rr = 0; rr < 4; ++rr) {
        acc[rr][0] = bv.x; acc[rr][1] = bv.y; acc[rr][2] = bv.z; acc[rr][3] = bv.w;
    }
#pragma unroll 8
    for (int k = 0; k < 64; ++k) {
        float4 zv = *reinterpret_cast<const float4*>(&zT[k * ZS + 4 * tr]);
        float4 wvv = w24[k * 16 + tc];
        const float zr[4] = {zv.x, zv.y, zv.z, zv.w};
        const float wc[4] = {wvv.x, wvv.y, wvv.z, wvv.w};
#pragma unroll
        for (int rr = 0; rr < 4; ++rr)
#pragma unroll
            for (int jj = 0; jj < 4; ++jj)
                acc[rr][jj] = fmaf(zr[rr], wc[jj], acc[rr][jj]);
    }

    // ---- store bf16 ----
    ushort4* ho4 = reinterpret_cast<ushort4*>(houtb);
#pragma unroll
    for (int rr = 0; rr < 4; ++rr) {
        int row = base + 4 * tr + rr;
        if (row < NN) {
            float ox = acc[rr][0], oy = acc[rr][1], oz = acc[rr][2], ow = acc[rr][3];
            if (relu_out) {
                ox = fmaxf(ox, 0.f); oy = fmaxf(oy, 0.f);
                oz = fmaxf(oz, 0.f); ow = fmaxf(ow, 0.f);
            }
            ushort4 o;
            o.x = f2b(ox); o.y = f2b(oy); o.z = f2b(oz); o.w = f2b(ow);
            ho4[(size_t)row * 16 + tc] = o;
        }
    }
}

// ---------------------------------------------------------------------------
// Pool + FC over bf16 h: one block per graph; batch sorted -> binary search.
// ---------------------------------------------------------------------------
__device__ __forceinline__ int lower_bound_i(const int* __restrict__ a, int n, int v) {
    int lo = 0, hi = n;
    while (lo < hi) {
        int mid = (lo + hi) >> 1;
        if (a[mid] < v) lo = mid + 1; else hi = mid;
    }
    return lo;
}

__global__ __launch_bounds__(256) void pool_k(const unsigned short* __restrict__ hb,
                                              const int* __restrict__ batch,
                                              const float* __restrict__ fcw,
                                              const float* __restrict__ fcb,
                                              float* __restrict__ out) {
    int g = blockIdx.x;
    int lane = threadIdx.x & 63;
    int wv = threadIdx.x >> 6;
    int lo = lower_bound_i(batch, NN, g);
    int hi = lower_bound_i(batch, NN, g + 1);
    float w = fcw[lane];
    float sum = 0.0f;
    for (int node = lo + wv; node < hi; node += 4)
        sum += b2f(hb[(size_t)node * 64 + lane]) * w;
#pragma unroll
    for (int off = 32; off > 0; off >>= 1) sum += __shfl_down(sum, off, 64);
    __shared__ float ws[4];
    if (lane == 0) ws[wv] = sum;
    __syncthreads();
    if (threadIdx.x == 0) out[g] = ws[0] + ws[1] + ws[2] + ws[3] + fcb[0];
}

extern "C" void kernel_launch(void* const* d_in, const int* in_sizes, int n_in,
                              void* d_out, int out_size, void* d_ws, size_t ws_size,
                              hipStream_t stream) {
    const float* x = (const float*)d_in[0];
    const int* ei = (const int*)d_in[1];     // [2, E] flat: src = ei[e], dst = ei[E+e]
    const int* batch = (const int*)d_in[2];  // [N], sorted
    const float* w[3][4];
    for (int l = 0; l < 3; ++l)
        for (int i = 0; i < 4; ++i) w[l][i] = (const float*)d_in[3 + l * 4 + i];
    const float* fcw = (const float*)d_in[15];
    const float* fcb = (const float*)d_in[16];
    float* out = (float*)d_out;

    // workspace layout
    unsigned short* P = (unsigned short*)d_ws;   // N*D bf16 (12.8 MB), aliases pairs
    unsigned short* Q = P + (size_t)NN * DD;     // N*D bf16 (12.8 MB)
    int* rowptr = (int*)(Q + (size_t)NN * DD);   // N+1 ints
    int* csr_src = rowptr + NN + 1;              // E ints (6.4 MB)
    int* gbkt = csr_src + NE;                    // NBKT ints
    int* bbase = gbkt + NBKT;                    // NBKT ints
    int* bcur = bbase + NBKT;                    // NBKT ints
    // pairs alias P (both exactly 12.8 MB): consumed by bfill_k before xconv_k
    int2* pairs = (int2*)P;

    // Build CSR (dst-bucketed counting sort); amortized over 3 layers.
    hipMemsetAsync(gbkt, 0, NBKT * sizeof(int), stream);
    bhist_k<<<NEB, 256, 0, stream>>>(ei, gbkt);
    bscan_k<<<1, 512, 0, stream>>>(gbkt, bbase, bcur);
    pscat_k<<<NEB, 256, 0, stream>>>(ei, bcur, pairs);
    bfill_k<<<NBKT, 256, 0, stream>>>(pairs, bbase, gbkt, rowptr, csr_src);

    // x -> bf16 (pairs dead now)
    xconv_k<<<(NN * 16 + 255) / 256, 256, 0, stream>>>(x, P);

    dim3 lgrid((NN + 63) / 64), lblk(256);
    // layer 0: self from fp32 x, gather from bf16 P -> Q
    gin_layer_k<<<lgrid, lblk, 0, stream>>>(x, P, rowptr, csr_src,
                                            w[0][0], w[0][1], w[0][2], w[0][3], Q, 1);
    // layer 1: bf16 Q -> P
    gin_layer_k<<<lgrid, lblk, 0, stream>>>(nullptr, Q, rowptr, csr_src,
                                            w[1][0], w[1][1], w[1][2], w[1][3], P, 1);
    // layer 2: bf16 P -> Q (no relu)
    gin_layer_k<<<lgrid, lblk, 0, stream>>>(nullptr, P, rowptr, csr_src,
                                            w[2][0], w[2][1], w[2][2], w[2][3], Q, 0);

    pool_k<<<NG, 256, 0, stream>>>(Q, batch, fcw, fcb, out);
}

// Round 8
// 418.682 us; speedup vs baseline: 1.1387x; 1.1387x over previous
//
#include <hip/hip_runtime.h>

constexpr int NN = 100000;   // nodes
constexpr int NE = 1600000;  // edges
constexpr int DD = 64;       // channels
constexpr int NG = 256;      // graphs

constexpr int BKT_SHIFT = 8;                   // 256 nodes per bucket
constexpr int NBKT = (NN + 255) >> BKT_SHIFT;  // 391 buckets
constexpr int EPB = 4096;                      // edges per block (build kernels)
constexpr int NEB = (NE + EPB - 1) / EPB;      // 391 blocks
constexpr int CAP = 16384;                     // pair window per bucket (mean 4092)

// ---------------------------------------------------------------------------
// bf16 helpers (manual, RNE)
// ---------------------------------------------------------------------------
__device__ __forceinline__ float b2f(unsigned short u) {
    union { unsigned int u; float f; } c;
    c.u = ((unsigned int)u) << 16;
    return c.f;
}
__device__ __forceinline__ unsigned short f2b(float f) {
    union { float f; unsigned int u; } c;
    c.f = f;
    unsigned int u = c.u + 0x7fff + ((c.u >> 16) & 1);
    return (unsigned short)(u >> 16);
}
__device__ __forceinline__ float lo16(unsigned int u) {
    union { unsigned int u; float f; } c;
    c.u = u << 16;
    return c.f;
}
__device__ __forceinline__ float hi16(unsigned int u) {
    union { unsigned int u; float f; } c;
    c.u = u & 0xffff0000u;
    return c.f;
}
__device__ __forceinline__ unsigned int pk(float a, float b) {
    return ((unsigned int)f2b(a)) | (((unsigned int)f2b(b)) << 16);
}

// ---------------------------------------------------------------------------
// CSR build. No global histogram pass: buckets get fixed-capacity windows
// (CAP=16K vs mean 4092 — uniform input, guarded against overflow).
// pairs packed: src (17 bits) | local-dst (8 bits) << 17.
// ---------------------------------------------------------------------------
__global__ __launch_bounds__(256) void pscat_k(const int* __restrict__ ei,
                                               int* __restrict__ gcnt,
                                               int* __restrict__ pairs) {
    __shared__ int lc[NBKT];
    __shared__ int gb[NBKT];
    for (int i = threadIdx.x; i < NBKT; i += 256) lc[i] = 0;
    __syncthreads();
    int base = blockIdx.x * EPB;
    int end = min(base + EPB, NE);
    for (int e = base + threadIdx.x; e < end; e += 256)
        atomicAdd(&lc[ei[NE + e] >> BKT_SHIFT], 1);
    __syncthreads();
    for (int i = threadIdx.x; i < NBKT; i += 256) {
        int c = lc[i];
        gb[i] = c ? atomicAdd(&gcnt[i], c) : 0;  // reserve exclusive window
    }
    __syncthreads();
    for (int i = threadIdx.x; i < NBKT; i += 256) lc[i] = 0;  // reuse as cursor
    __syncthreads();
    for (int e = base + threadIdx.x; e < end; e += 256) {
        int src = ei[e];
        int dst = ei[NE + e];
        int b = dst >> BKT_SHIFT;
        int pos = gb[b] + atomicAdd(&lc[b], 1);
        if (pos < CAP)
            pairs[(size_t)b * CAP + pos] = src | ((dst & 255) << 17);
    }
}

__global__ __launch_bounds__(512) void bscan_k(const int* __restrict__ gcnt,
                                               int* __restrict__ bbase) {
    __shared__ int sh[512];
    int t = threadIdx.x;
    int v = (t < NBKT) ? min(gcnt[t], CAP) : 0;
    sh[t] = v;
    __syncthreads();
    for (int off = 1; off < 512; off <<= 1) {
        int u = (t >= off) ? sh[t - off] : 0;
        __syncthreads();
        sh[t] += u;
        __syncthreads();
    }
    if (t < NBKT) bbase[t] = sh[t] - v;
}

__global__ __launch_bounds__(256) void bfill_k(const int* __restrict__ pairs,
                                               const int* __restrict__ bbase,
                                               const int* __restrict__ gcnt,
                                               int* __restrict__ rowptr,
                                               int* __restrict__ csr_src) {
    __shared__ int ldeg[256];
    __shared__ int sh[256];
    __shared__ int lcur[256];
    int b = blockIdx.x;
    int t = threadIdx.x;
    int pcnt = min(gcnt[b], CAP);
    const int* pw = pairs + (size_t)b * CAP;
    int cbeg = bbase[b];
    ldeg[t] = 0;
    __syncthreads();
    for (int i = t; i < pcnt; i += 256)
        atomicAdd(&ldeg[(pw[i] >> 17) & 255], 1);
    __syncthreads();
    int v = ldeg[t];
    sh[t] = v;
    __syncthreads();
    for (int off = 1; off < 256; off <<= 1) {
        int u = (t >= off) ? sh[t - off] : 0;
        __syncthreads();
        sh[t] += u;
        __syncthreads();
    }
    int lexcl = sh[t] - v;
    int node = (b << BKT_SHIFT) + t;
    if (node < NN) {
        rowptr[node] = cbeg + lexcl;
        if (node == NN - 1) rowptr[NN] = cbeg + lexcl + v;
    }
    lcur[t] = lexcl;
    __syncthreads();
    for (int i = t; i < pcnt; i += 256) {
        int p = pw[i];
        int pos = atomicAdd(&lcur[(p >> 17) & 255], 1);
        csr_src[cbeg + pos] = p & 0x1FFFF;
    }
}

// ---------------------------------------------------------------------------
// x (fp32) -> bf16.
// ---------------------------------------------------------------------------
__global__ __launch_bounds__(256) void xconv_k(const float* __restrict__ x,
                                               unsigned short* __restrict__ xb) {
    int i = blockIdx.x * 256 + threadIdx.x;  // float4 groups, NN*16 total
    if (i < NN * 16) {
        float4 v = reinterpret_cast<const float4*>(x)[i];
        ushort4 o;
        o.x = f2b(v.x); o.y = f2b(v.y); o.z = f2b(v.z); o.w = f2b(v.w);
        reinterpret_cast<ushort4*>(xb)[i] = o;
    }
}

// ---------------------------------------------------------------------------
// Gather + self term -> z (bf16). One wave per node. bf16 row = 8 x uint4;
// 8 lanes cover a row, 8 edge-groups per wave -> 1 KB per load instruction.
// fp32 accumulate; 3 shuffle rounds combine the 8 groups; lanes 0-7 store.
// ---------------------------------------------------------------------------
__global__ __launch_bounds__(256) void gather_k(const uint4* __restrict__ hb4,
                                                const float4* __restrict__ selff,
                                                const int* __restrict__ rowptr,
                                                const int* __restrict__ csr_src,
                                                uint4* __restrict__ zb4) {
    int node = blockIdx.x * 4 + (threadIdx.x >> 6);
    if (node >= NN) return;
    int lane = threadIdx.x & 63;
    int c = lane & 7;    // 16 B chunk (8 channels)
    int grp = lane >> 3; // edge group 0..7
    int beg = rowptr[node];
    int end = rowptr[node + 1];
    float a0 = 0, a1 = 0, a2 = 0, a3 = 0, a4 = 0, a5 = 0, a6 = 0, a7 = 0;
    for (int i = beg + grp; i < end; i += 8) {
        uint4 v = hb4[(size_t)csr_src[i] * 8 + c];
        a0 += lo16(v.x); a1 += hi16(v.x);
        a2 += lo16(v.y); a3 += hi16(v.y);
        a4 += lo16(v.z); a5 += hi16(v.z);
        a6 += lo16(v.w); a7 += hi16(v.w);
    }
#pragma unroll
    for (int off = 32; off >= 8; off >>= 1) {
        a0 += __shfl_down(a0, off, 64);
        a1 += __shfl_down(a1, off, 64);
        a2 += __shfl_down(a2, off, 64);
        a3 += __shfl_down(a3, off, 64);
        a4 += __shfl_down(a4, off, 64);
        a5 += __shfl_down(a5, off, 64);
        a6 += __shfl_down(a6, off, 64);
        a7 += __shfl_down(a7, off, 64);
    }
    if (grp == 0) {
        if (selff) {
            float4 s0 = selff[(size_t)node * 16 + 2 * c];
            float4 s1 = selff[(size_t)node * 16 + 2 * c + 1];
            a0 += s0.x; a1 += s0.y; a2 += s0.z; a3 += s0.w;
            a4 += s1.x; a5 += s1.y; a6 += s1.z; a7 += s1.w;
        } else {
            uint4 sv = hb4[(size_t)node * 8 + c];
            a0 += lo16(sv.x); a1 += hi16(sv.x);
            a2 += lo16(sv.y); a3 += hi16(sv.y);
            a4 += lo16(sv.z); a5 += hi16(sv.z);
            a6 += lo16(sv.w); a7 += hi16(sv.w);
        }
        uint4 o;
        o.x = pk(a0, a1); o.y = pk(a2, a3); o.z = pk(a4, a5); o.w = pk(a6, a7);
        zb4[(size_t)node * 8 + c] = o;
    }
}

// ---------------------------------------------------------------------------
// 2-layer MLP on bf16 z -> bf16 h, register-blocked LDS-tiled GEMM
// (round-6 structure). Block 256, 64-row tile; zT fp32 in LDS (stride 68),
// weights staged w1 then w2 (33.4 KB LDS -> 4 blocks/CU).
// ---------------------------------------------------------------------------
constexpr int ZS = 68;

__global__ __launch_bounds__(256) void mlp_k(const uint4* __restrict__ zb4,
                                             const float* __restrict__ w1,
                                             const float* __restrict__ b1,
                                             const float* __restrict__ w2,
                                             const float* __restrict__ b2,
                                             ushort4* __restrict__ houtb,
                                             int relu_out) {
    __shared__ float zT[64 * ZS];   // [k][r]
    __shared__ float wsm[64 * 64];  // [k][j]
    int tid = threadIdx.x;
    int base = blockIdx.x * 64;

    // ---- stage z (bf16) transposed into zT (fp32) ----
    {
        int r = tid >> 2;    // 0..63
        int part = tid & 3;  // 0..3
        int row = base + r;
#pragma unroll
        for (int h = 0; h < 2; ++h) {
            int cc = part + 4 * h;  // uint4 chunk 0..7
            uint4 v = make_uint4(0, 0, 0, 0);
            if (row < NN) v = zb4[(size_t)row * 8 + cc];
            int ch = cc * 8;
            zT[(ch + 0) * ZS + r] = lo16(v.x);
            zT[(ch + 1) * ZS + r] = hi16(v.x);
            zT[(ch + 2) * ZS + r] = lo16(v.y);
            zT[(ch + 3) * ZS + r] = hi16(v.y);
            zT[(ch + 4) * ZS + r] = lo16(v.z);
            zT[(ch + 5) * ZS + r] = hi16(v.z);
            zT[(ch + 6) * ZS + r] = lo16(v.w);
            zT[(ch + 7) * ZS + r] = hi16(v.w);
        }
    }
    // ---- stage w1 ----
    {
        const float4* w4 = reinterpret_cast<const float4*>(w1);
        float4* s4 = reinterpret_cast<float4*>(wsm);
        for (int i = tid; i < 1024; i += 256) s4[i] = w4[i];
    }
    __syncthreads();

    int tr = tid & 15;  // rows 4tr..4tr+3
    int tc = tid >> 4;  // cols 4tc..4tc+3

    // ---- layer 1 ----
    float4 bv = reinterpret_cast<const float4*>(b1)[tc];
    float acc[4][4];
#pragma unroll
    for (int rr = 0; rr < 4; ++rr) {
        acc[rr][0] = bv.x; acc[rr][1] = bv.y; acc[rr][2] = bv.z; acc[rr][3] = bv.w;
    }
#pragma unroll 8
    for (int k = 0; k < 64; ++k) {
        float4 zv = *reinterpret_cast<const float4*>(&zT[k * ZS + 4 * tr]);
        float4 wv = *reinterpret_cast<const float4*>(&wsm[k * 64 + 4 * tc]);
        const float zr[4] = {zv.x, zv.y, zv.z, zv.w};
        const float wc[4] = {wv.x, wv.y, wv.z, wv.w};
#pragma unroll
        for (int rr = 0; rr < 4; ++rr)
#pragma unroll
            for (int jj = 0; jj < 4; ++jj)
                acc[rr][jj] = fmaf(zr[rr], wc[jj], acc[rr][jj]);
    }
    __syncthreads();

    // ---- h1 = ReLU(acc) transposed back into zT; stage w2 ----
#pragma unroll
    for (int jj = 0; jj < 4; ++jj) {
        float4 hv;
        hv.x = fmaxf(acc[0][jj], 0.f);
        hv.y = fmaxf(acc[1][jj], 0.f);
        hv.z = fmaxf(acc[2][jj], 0.f);
        hv.w = fmaxf(acc[3][jj], 0.f);
        *reinterpret_cast<float4*>(&zT[(4 * tc + jj) * ZS + 4 * tr]) = hv;
    }
    {
        const float4* w4 = reinterpret_cast<const float4*>(w2);
        float4* s4 = reinterpret_cast<float4*>(wsm);
        for (int i = tid; i < 1024; i += 256) s4[i] = w4[i];
    }
    __syncthreads();

    // ---- layer 2 ----
    bv = reinterpret_cast<const float4*>(b2)[tc];
#pragma unroll
    for (int rr = 0; rr < 4; ++rr) {
        acc[rr][0] = bv.x; acc[rr][1] = bv.y; acc[rr][2] = bv.z; acc[rr][3] = bv.w;
    }
#pragma unroll 8
    for (int k = 0; k < 64; ++k) {
        float4 zv = *reinterpret_cast<const float4*>(&zT[k * ZS + 4 * tr]);
        float4 wv = *reinterpret_cast<const float4*>(&wsm[k * 64 + 4 * tc]);
        const float zr[4] = {zv.x, zv.y, zv.z, zv.w};
        const float wc[4] = {wv.x, wv.y, wv.z, wv.w};
#pragma unroll
        for (int rr = 0; rr < 4; ++rr)
#pragma unroll
            for (int jj = 0; jj < 4; ++jj)
                acc[rr][jj] = fmaf(zr[rr], wc[jj], acc[rr][jj]);
    }

    // ---- store bf16 ----
#pragma unroll
    for (int rr = 0; rr < 4; ++rr) {
        int row = base + 4 * tr + rr;
        if (row < NN) {
            float ox = acc[rr][0], oy = acc[rr][1], oz = acc[rr][2], ow = acc[rr][3];
            if (relu_out) {
                ox = fmaxf(ox, 0.f); oy = fmaxf(oy, 0.f);
                oz = fmaxf(oz, 0.f); ow = fmaxf(ow, 0.f);
            }
            ushort4 o;
            o.x = f2b(ox); o.y = f2b(oy); o.z = f2b(oz); o.w = f2b(ow);
            houtb[(size_t)row * 16 + tc] = o;
        }
    }
}

// ---------------------------------------------------------------------------
// Pool + FC over bf16 h: one block per graph; batch sorted -> binary search.
// ---------------------------------------------------------------------------
__device__ __forceinline__ int lower_bound_i(const int* __restrict__ a, int n, int v) {
    int lo = 0, hi = n;
    while (lo < hi) {
        int mid = (lo + hi) >> 1;
        if (a[mid] < v) lo = mid + 1; else hi = mid;
    }
    return lo;
}

__global__ __launch_bounds__(256) void pool_k(const unsigned short* __restrict__ hb,
                                              const int* __restrict__ batch,
                                              const float* __restrict__ fcw,
                                              const float* __restrict__ fcb,
                                              float* __restrict__ out) {
    int g = blockIdx.x;
    int lane = threadIdx.x & 63;
    int wv = threadIdx.x >> 6;
    int lo = lower_bound_i(batch, NN, g);
    int hi = lower_bound_i(batch, NN, g + 1);
    float w = fcw[lane];
    float sum = 0.0f;
    for (int node = lo + wv; node < hi; node += 4)
        sum += b2f(hb[(size_t)node * 64 + lane]) * w;
#pragma unroll
    for (int off = 32; off > 0; off >>= 1) sum += __shfl_down(sum, off, 64);
    __shared__ float ws[4];
    if (lane == 0) ws[wv] = sum;
    __syncthreads();
    if (threadIdx.x == 0) out[g] = ws[0] + ws[1] + ws[2] + ws[3] + fcb[0];
}

extern "C" void kernel_launch(void* const* d_in, const int* in_sizes, int n_in,
                              void* d_out, int out_size, void* d_ws, size_t ws_size,
                              hipStream_t stream) {
    const float* x = (const float*)d_in[0];
    const int* ei = (const int*)d_in[1];     // [2, E] flat: src = ei[e], dst = ei[E+e]
    const int* batch = (const int*)d_in[2];  // [N], sorted
    const float* w[3][4];
    for (int l = 0; l < 3; ++l)
        for (int i = 0; i < 4; ++i) w[l][i] = (const float*)d_in[3 + l * 4 + i];
    const float* fcw = (const float*)d_in[15];
    const float* fcb = (const float*)d_in[16];
    float* out = (float*)d_out;

    // workspace layout (~45 MB)
    int* pairs = (int*)d_ws;                               // NBKT*CAP ints (25.6 MB)
    unsigned short* Z = (unsigned short*)d_ws;             // bf16 z, aliases pairs
    unsigned short* H = (unsigned short*)((char*)d_ws + (size_t)NBKT * CAP * 4);  // bf16 h (12.8 MB)
    int* rowptr = (int*)(H + (size_t)NN * DD);             // N+1
    int* csr_src = rowptr + NN + 1;                        // NE (6.4 MB)
    int* gcnt = csr_src + NE;                              // NBKT
    int* bbase = gcnt + NBKT;                              // NBKT

    // Build CSR; pairs consumed by bfill before Z is first written.
    hipMemsetAsync(gcnt, 0, NBKT * sizeof(int), stream);
    pscat_k<<<NEB, 256, 0, stream>>>(ei, gcnt, pairs);
    bscan_k<<<1, 512, 0, stream>>>(gcnt, bbase);
    bfill_k<<<NBKT, 256, 0, stream>>>(pairs, bbase, gcnt, rowptr, csr_src);

    // x -> bf16 H
    xconv_k<<<(NN * 16 + 255) / 256, 256, 0, stream>>>(x, H);

    dim3 ggrid((NN + 3) / 4), mgrid((NN + 63) / 64);
    // L0: gather(H=xb, self=x fp32) -> Z; mlp(Z) -> H (relu)
    gather_k<<<ggrid, 256, 0, stream>>>((const uint4*)H, (const float4*)x, rowptr,
                                        csr_src, (uint4*)Z);
    mlp_k<<<mgrid, 256, 0, stream>>>((const uint4*)Z, w[0][0], w[0][1], w[0][2],
                                     w[0][3], (ushort4*)H, 1);
    // L1
    gather_k<<<ggrid, 256, 0, stream>>>((const uint4*)H, nullptr, rowptr, csr_src,
                                        (uint4*)Z);
    mlp_k<<<mgrid, 256, 0, stream>>>((const uint4*)Z, w[1][0], w[1][1], w[1][2],
                                     w[1][3], (ushort4*)H, 1);
    // L2 (no relu)
    gather_k<<<ggrid, 256, 0, stream>>>((const uint4*)H, nullptr, rowptr, csr_src,
                                        (uint4*)Z);
    mlp_k<<<mgrid, 256, 0, stream>>>((const uint4*)Z, w[2][0], w[2][1], w[2][2],
                                     w[2][3], (ushort4*)H, 0);

    pool_k<<<NG, 256, 0, stream>>>(H, batch, fcw, fcb, out);
}

// Round 9
// 399.042 us; speedup vs baseline: 1.1947x; 1.0492x over previous
//
#include <hip/hip_runtime.h>

constexpr int NN = 100000;   // nodes
constexpr int NE = 1600000;  // edges
constexpr int DD = 64;       // channels
constexpr int NG = 256;      // graphs

constexpr int BKT_SHIFT = 8;                   // 256 nodes per bucket
constexpr int NBKT = (NN + 255) >> BKT_SHIFT;  // 391 buckets
constexpr int EPB = 4096;                      // edges per block (build kernels)
constexpr int NEB = (NE + EPB - 1) / EPB;      // 391 blocks
constexpr int CAP = 16384;                     // pair window per bucket (mean 4092)

// ---------------------------------------------------------------------------
// bf16 helpers (manual, RNE)
// ---------------------------------------------------------------------------
__device__ __forceinline__ float b2f(unsigned short u) {
    union { unsigned int u; float f; } c;
    c.u = ((unsigned int)u) << 16;
    return c.f;
}
__device__ __forceinline__ unsigned short f2b(float f) {
    union { float f; unsigned int u; } c;
    c.f = f;
    unsigned int u = c.u + 0x7fff + ((c.u >> 16) & 1);
    return (unsigned short)(u >> 16);
}
__device__ __forceinline__ float lo16(unsigned int u) {
    union { unsigned int u; float f; } c;
    c.u = u << 16;
    return c.f;
}
__device__ __forceinline__ float hi16(unsigned int u) {
    union { unsigned int u; float f; } c;
    c.u = u & 0xffff0000u;
    return c.f;
}
__device__ __forceinline__ unsigned int pk(float a, float b) {
    return ((unsigned int)f2b(a)) | (((unsigned int)f2b(b)) << 16);
}

// ---------------------------------------------------------------------------
// CSR build. pscat: ONE global pass — stage packed edges + bucket id in LDS,
// histogram, reserve windows, scatter from LDS.
// pairs packed: src (17 bits) | local-dst (8 bits) << 17.
// ---------------------------------------------------------------------------
__global__ __launch_bounds__(256) void pscat_k(const int* __restrict__ ei,
                                               int* __restrict__ gcnt,
                                               int* __restrict__ pairs) {
    __shared__ int lc[NBKT];
    __shared__ int gb[NBKT];
    __shared__ int pe[EPB];
    __shared__ unsigned short pb[EPB];
    int tid = threadIdx.x;
    for (int i = tid; i < NBKT; i += 256) lc[i] = 0;
    __syncthreads();
    int base = blockIdx.x * EPB;
    int n = min(base + EPB, NE) - base;
    for (int t = tid; t < n; t += 256) {
        int src = ei[base + t];
        int dst = ei[NE + base + t];
        int b = dst >> BKT_SHIFT;
        pe[t] = src | ((dst & 255) << 17);
        pb[t] = (unsigned short)b;
        atomicAdd(&lc[b], 1);
    }
    __syncthreads();
    for (int i = tid; i < NBKT; i += 256) {
        int c = lc[i];
        gb[i] = c ? atomicAdd(&gcnt[i], c) : 0;  // reserve exclusive window
    }
    __syncthreads();
    for (int i = tid; i < NBKT; i += 256) lc[i] = 0;  // reuse as cursor
    __syncthreads();
    for (int t = tid; t < n; t += 256) {
        int b = pb[t];
        int pos = gb[b] + atomicAdd(&lc[b], 1);
        if (pos < CAP) pairs[(size_t)b * CAP + pos] = pe[t];
    }
}

__global__ __launch_bounds__(512) void bscan_k(const int* __restrict__ gcnt,
                                               int* __restrict__ bbase) {
    __shared__ int sh[512];
    int t = threadIdx.x;
    int v = (t < NBKT) ? min(gcnt[t], CAP) : 0;
    sh[t] = v;
    __syncthreads();
    for (int off = 1; off < 512; off <<= 1) {
        int u = (t >= off) ? sh[t - off] : 0;
        __syncthreads();
        sh[t] += u;
        __syncthreads();
    }
    if (t < NBKT) bbase[t] = sh[t] - v;
}

__global__ __launch_bounds__(256) void bfill_k(const int* __restrict__ pairs,
                                               const int* __restrict__ bbase,
                                               const int* __restrict__ gcnt,
                                               int* __restrict__ rowptr,
                                               int* __restrict__ csr_src) {
    __shared__ int ldeg[256];
    __shared__ int sh[256];
    __shared__ int lcur[256];
    int b = blockIdx.x;
    int t = threadIdx.x;
    int pcnt = min(gcnt[b], CAP);
    const int* pw = pairs + (size_t)b * CAP;
    int cbeg = bbase[b];
    ldeg[t] = 0;
    __syncthreads();
    for (int i = t; i < pcnt; i += 256)
        atomicAdd(&ldeg[(pw[i] >> 17) & 255], 1);
    __syncthreads();
    int v = ldeg[t];
    sh[t] = v;
    __syncthreads();
    for (int off = 1; off < 256; off <<= 1) {
        int u = (t >= off) ? sh[t - off] : 0;
        __syncthreads();
        sh[t] += u;
        __syncthreads();
    }
    int lexcl = sh[t] - v;
    int node = (b << BKT_SHIFT) + t;
    if (node < NN) {
        rowptr[node] = cbeg + lexcl;
        if (node == NN - 1) rowptr[NN] = cbeg + lexcl + v;
    }
    lcur[t] = lexcl;
    __syncthreads();
    for (int i = t; i < pcnt; i += 256) {
        int p = pw[i];
        int pos = atomicAdd(&lcur[(p >> 17) & 255], 1);
        csr_src[cbeg + pos] = p & 0x1FFFF;
    }
}

// ---------------------------------------------------------------------------
// x (fp32) -> bf16.
// ---------------------------------------------------------------------------
__global__ __launch_bounds__(256) void xconv_k(const float* __restrict__ x,
                                               unsigned short* __restrict__ xb) {
    int i = blockIdx.x * 256 + threadIdx.x;  // float4 groups, NN*16 total
    if (i < NN * 16) {
        float4 v = reinterpret_cast<const float4*>(x)[i];
        ushort4 o;
        o.x = f2b(v.x); o.y = f2b(v.y); o.z = f2b(v.z); o.w = f2b(v.w);
        reinterpret_cast<ushort4*>(xb)[i] = o;
    }
}

// ---------------------------------------------------------------------------
// Gather + self term -> z (bf16). One wave per node, 8 lanes x uint4 per row,
// 8 edge groups. Indices PREFETCHED: one coalesced load of up to 64 idx, then
// __shfl broadcast -> all row loads independent; explicit 2-stage pipeline.
// ---------------------------------------------------------------------------
__global__ __launch_bounds__(256) void gather_k(const uint4* __restrict__ hb4,
                                                const float4* __restrict__ selff,
                                                const int* __restrict__ rowptr,
                                                const int* __restrict__ csr_src,
                                                uint4* __restrict__ zb4) {
    int node = blockIdx.x * 4 + (threadIdx.x >> 6);
    if (node >= NN) return;
    int lane = threadIdx.x & 63;
    int c = lane & 7;    // 16 B chunk (8 channels)
    int grp = lane >> 3; // edge group 0..7
    int beg = rowptr[node];
    int end = rowptr[node + 1];
    int deg = end - beg;
    float a0 = 0, a1 = 0, a2 = 0, a3 = 0, a4 = 0, a5 = 0, a6 = 0, a7 = 0;

    if (deg <= 64) {
        int idx = 0;
        if (lane < deg) idx = csr_src[beg + lane];  // one coalesced index load
        int nit = (deg + 7) >> 3;
        if (nit > 0) {
            // stage 0
            int k0 = grp;
            int s0 = __shfl(idx, k0, 64);
            uint4 v0 = make_uint4(0, 0, 0, 0);
            if (k0 < deg) v0 = hb4[(size_t)s0 * 8 + c];
            for (int j = 1; j < nit; ++j) {
                int k1 = grp + (j << 3);
                int s1 = __shfl(idx, k1, 64);
                uint4 v1 = make_uint4(0, 0, 0, 0);
                if (k1 < deg) v1 = hb4[(size_t)s1 * 8 + c];  // issue before consuming v0
                a0 += lo16(v0.x); a1 += hi16(v0.x);
                a2 += lo16(v0.y); a3 += hi16(v0.y);
                a4 += lo16(v0.z); a5 += hi16(v0.z);
                a6 += lo16(v0.w); a7 += hi16(v0.w);
                v0 = v1;
            }
            a0 += lo16(v0.x); a1 += hi16(v0.x);
            a2 += lo16(v0.y); a3 += hi16(v0.y);
            a4 += lo16(v0.z); a5 += hi16(v0.z);
            a6 += lo16(v0.w); a7 += hi16(v0.w);
        }
    } else {
        for (int i = beg + grp; i < end; i += 8) {
            uint4 v = hb4[(size_t)csr_src[i] * 8 + c];
            a0 += lo16(v.x); a1 += hi16(v.x);
            a2 += lo16(v.y); a3 += hi16(v.y);
            a4 += lo16(v.z); a5 += hi16(v.z);
            a6 += lo16(v.w); a7 += hi16(v.w);
        }
    }
#pragma unroll
    for (int off = 32; off >= 8; off >>= 1) {
        a0 += __shfl_down(a0, off, 64);
        a1 += __shfl_down(a1, off, 64);
        a2 += __shfl_down(a2, off, 64);
        a3 += __shfl_down(a3, off, 64);
        a4 += __shfl_down(a4, off, 64);
        a5 += __shfl_down(a5, off, 64);
        a6 += __shfl_down(a6, off, 64);
        a7 += __shfl_down(a7, off, 64);
    }
    if (grp == 0) {
        if (selff) {
            float4 s0 = selff[(size_t)node * 16 + 2 * c];
            float4 s1 = selff[(size_t)node * 16 + 2 * c + 1];
            a0 += s0.x; a1 += s0.y; a2 += s0.z; a3 += s0.w;
            a4 += s1.x; a5 += s1.y; a6 += s1.z; a7 += s1.w;
        } else {
            uint4 sv = hb4[(size_t)node * 8 + c];
            a0 += lo16(sv.x); a1 += hi16(sv.x);
            a2 += lo16(sv.y); a3 += hi16(sv.y);
            a4 += lo16(sv.z); a5 += hi16(sv.z);
            a6 += lo16(sv.w); a7 += hi16(sv.w);
        }
        uint4 o;
        o.x = pk(a0, a1); o.y = pk(a2, a3); o.z = pk(a4, a5); o.w = pk(a6, a7);
        zb4[(size_t)node * 8 + c] = o;
    }
}

// ---------------------------------------------------------------------------
// 2-layer MLP on bf16 z -> bf16 h, register-blocked LDS-tiled GEMM.
// ---------------------------------------------------------------------------
constexpr int ZS = 68;

__global__ __launch_bounds__(256) void mlp_k(const uint4* __restrict__ zb4,
                                             const float* __restrict__ w1,
                                             const float* __restrict__ b1,
                                             const float* __restrict__ w2,
                                             const float* __restrict__ b2,
                                             ushort4* __restrict__ houtb,
                                             int relu_out) {
    __shared__ float zT[64 * ZS];   // [k][r]
    __shared__ float wsm[64 * 64];  // [k][j]
    int tid = threadIdx.x;
    int base = blockIdx.x * 64;

    // ---- stage z (bf16) transposed into zT (fp32) ----
    {
        int r = tid >> 2;    // 0..63
        int part = tid & 3;  // 0..3
        int row = base + r;
#pragma unroll
        for (int h = 0; h < 2; ++h) {
            int cc = part + 4 * h;  // uint4 chunk 0..7
            uint4 v = make_uint4(0, 0, 0, 0);
            if (row < NN) v = zb4[(size_t)row * 8 + cc];
            int ch = cc * 8;
            zT[(ch + 0) * ZS + r] = lo16(v.x);
            zT[(ch + 1) * ZS + r] = hi16(v.x);
            zT[(ch + 2) * ZS + r] = lo16(v.y);
            zT[(ch + 3) * ZS + r] = hi16(v.y);
            zT[(ch + 4) * ZS + r] = lo16(v.z);
            zT[(ch + 5) * ZS + r] = hi16(v.z);
            zT[(ch + 6) * ZS + r] = lo16(v.w);
            zT[(ch + 7) * ZS + r] = hi16(v.w);
        }
    }
    // ---- stage w1 ----
    {
        const float4* w4 = reinterpret_cast<const float4*>(w1);
        float4* s4 = reinterpret_cast<float4*>(wsm);
        for (int i = tid; i < 1024; i += 256) s4[i] = w4[i];
    }
    __syncthreads();

    int tr = tid & 15;  // rows 4tr..4tr+3
    int tc = tid >> 4;  // cols 4tc..4tc+3

    // ---- layer 1 ----
    float4 bv = reinterpret_cast<const float4*>(b1)[tc];
    float acc[4][4];
#pragma unroll
    for (int rr = 0; rr < 4; ++rr) {
        acc[rr][0] = bv.x; acc[rr][1] = bv.y; acc[rr][2] = bv.z; acc[rr][3] = bv.w;
    }
#pragma unroll 8
    for (int k = 0; k < 64; ++k) {
        float4 zv = *reinterpret_cast<const float4*>(&zT[k * ZS + 4 * tr]);
        float4 wv = *reinterpret_cast<const float4*>(&wsm[k * 64 + 4 * tc]);
        const float zr[4] = {zv.x, zv.y, zv.z, zv.w};
        const float wc[4] = {wv.x, wv.y, wv.z, wv.w};
#pragma unroll
        for (int rr = 0; rr < 4; ++rr)
#pragma unroll
            for (int jj = 0; jj < 4; ++jj)
                acc[rr][jj] = fmaf(zr[rr], wc[jj], acc[rr][jj]);
    }
    __syncthreads();

    // ---- h1 = ReLU(acc) transposed back into zT; stage w2 ----
#pragma unroll
    for (int jj = 0; jj < 4; ++jj) {
        float4 hv;
        hv.x = fmaxf(acc[0][jj], 0.f);
        hv.y = fmaxf(acc[1][jj], 0.f);
        hv.z = fmaxf(acc[2][jj], 0.f);
        hv.w = fmaxf(acc[3][jj], 0.f);
        *reinterpret_cast<float4*>(&zT[(4 * tc + jj) * ZS + 4 * tr]) = hv;
    }
    {
        const float4* w4 = reinterpret_cast<const float4*>(w2);
        float4* s4 = reinterpret_cast<float4*>(wsm);
        for (int i = tid; i < 1024; i += 256) s4[i] = w4[i];
    }
    __syncthreads();

    // ---- layer 2 ----
    bv = reinterpret_cast<const float4*>(b2)[tc];
#pragma unroll
    for (int rr = 0; rr < 4; ++rr) {
        acc[rr][0] = bv.x; acc[rr][1] = bv.y; acc[rr][2] = bv.z; acc[rr][3] = bv.w;
    }
#pragma unroll 8
    for (int k = 0; k < 64; ++k) {
        float4 zv = *reinterpret_cast<const float4*>(&zT[k * ZS + 4 * tr]);
        float4 wv = *reinterpret_cast<const float4*>(&wsm[k * 64 + 4 * tc]);
        const float zr[4] = {zv.x, zv.y, zv.z, zv.w};
        const float wc[4] = {wv.x, wv.y, wv.z, wv.w};
#pragma unroll
        for (int rr = 0; rr < 4; ++rr)
#pragma unroll
            for (int jj = 0; jj < 4; ++jj)
                acc[rr][jj] = fmaf(zr[rr], wc[jj], acc[rr][jj]);
    }

    // ---- store bf16 ----
#pragma unroll
    for (int rr = 0; rr < 4; ++rr) {
        int row = base + 4 * tr + rr;
        if (row < NN) {
            float ox = acc[rr][0], oy = acc[rr][1], oz = acc[rr][2], ow = acc[rr][3];
            if (relu_out) {
                ox = fmaxf(ox, 0.f); oy = fmaxf(oy, 0.f);
                oz = fmaxf(oz, 0.f); ow = fmaxf(ow, 0.f);
            }
            ushort4 o;
            o.x = f2b(ox); o.y = f2b(oy); o.z = f2b(oz); o.w = f2b(ow);
            houtb[(size_t)row * 16 + tc] = o;
        }
    }
}

// ---------------------------------------------------------------------------
// Pool + FC over bf16 h: one block per graph; batch sorted -> binary search.
// ---------------------------------------------------------------------------
__device__ __forceinline__ int lower_bound_i(const int* __restrict__ a, int n, int v) {
    int lo = 0, hi = n;
    while (lo < hi) {
        int mid = (lo + hi) >> 1;
        if (a[mid] < v) lo = mid + 1; else hi = mid;
    }
    return lo;
}

__global__ __launch_bounds__(256) void pool_k(const unsigned short* __restrict__ hb,
                                              const int* __restrict__ batch,
                                              const float* __restrict__ fcw,
                                              const float* __restrict__ fcb,
                                              float* __restrict__ out) {
    int g = blockIdx.x;
    int lane = threadIdx.x & 63;
    int wv = threadIdx.x >> 6;
    int lo = lower_bound_i(batch, NN, g);
    int hi = lower_bound_i(batch, NN, g + 1);
    float w = fcw[lane];
    float sum = 0.0f;
    for (int node = lo + wv; node < hi; node += 4)
        sum += b2f(hb[(size_t)node * 64 + lane]) * w;
#pragma unroll
    for (int off = 32; off > 0; off >>= 1) sum += __shfl_down(sum, off, 64);
    __shared__ float ws[4];
    if (lane == 0) ws[wv] = sum;
    __syncthreads();
    if (threadIdx.x == 0) out[g] = ws[0] + ws[1] + ws[2] + ws[3] + fcb[0];
}

extern "C" void kernel_launch(void* const* d_in, const int* in_sizes, int n_in,
                              void* d_out, int out_size, void* d_ws, size_t ws_size,
                              hipStream_t stream) {
    const float* x = (const float*)d_in[0];
    const int* ei = (const int*)d_in[1];     // [2, E] flat: src = ei[e], dst = ei[E+e]
    const int* batch = (const int*)d_in[2];  // [N], sorted
    const float* w[3][4];
    for (int l = 0; l < 3; ++l)
        for (int i = 0; i < 4; ++i) w[l][i] = (const float*)d_in[3 + l * 4 + i];
    const float* fcw = (const float*)d_in[15];
    const float* fcb = (const float*)d_in[16];
    float* out = (float*)d_out;

    // workspace layout (~45 MB)
    int* pairs = (int*)d_ws;                               // NBKT*CAP ints (25.6 MB)
    unsigned short* Z = (unsigned short*)d_ws;             // bf16 z, aliases pairs
    unsigned short* H = (unsigned short*)((char*)d_ws + (size_t)NBKT * CAP * 4);  // bf16 h (12.8 MB)
    int* rowptr = (int*)(H + (size_t)NN * DD);             // N+1
    int* csr_src = rowptr + NN + 1;                        // NE (6.4 MB)
    int* gcnt = csr_src + NE;                              // NBKT
    int* bbase = gcnt + NBKT;                              // NBKT

    // Build CSR; pairs consumed by bfill before Z is first written.
    hipMemsetAsync(gcnt, 0, NBKT * sizeof(int), stream);
    pscat_k<<<NEB, 256, 0, stream>>>(ei, gcnt, pairs);
    bscan_k<<<1, 512, 0, stream>>>(gcnt, bbase);
    bfill_k<<<NBKT, 256, 0, stream>>>(pairs, bbase, gcnt, rowptr, csr_src);

    // x -> bf16 H
    xconv_k<<<(NN * 16 + 255) / 256, 256, 0, stream>>>(x, H);

    dim3 ggrid((NN + 3) / 4), mgrid((NN + 63) / 64);
    // L0: gather(H=xb, self=x fp32) -> Z; mlp(Z) -> H (relu)
    gather_k<<<ggrid, 256, 0, stream>>>((const uint4*)H, (const float4*)x, rowptr,
                                        csr_src, (uint4*)Z);
    mlp_k<<<mgrid, 256, 0, stream>>>((const uint4*)Z, w[0][0], w[0][1], w[0][2],
                                     w[0][3], (ushort4*)H, 1);
    // L1
    gather_k<<<ggrid, 256, 0, stream>>>((const uint4*)H, nullptr, rowptr, csr_src,
                                        (uint4*)Z);
    mlp_k<<<mgrid, 256, 0, stream>>>((const uint4*)Z, w[1][0], w[1][1], w[1][2],
                                     w[1][3], (ushort4*)H, 1);
    // L2 (no relu)
    gather_k<<<ggrid, 256, 0, stream>>>((const uint4*)H, nullptr, rowptr, csr_src,
                                        (uint4*)Z);
    mlp_k<<<mgrid, 256, 0, stream>>>((const uint4*)Z, w[2][0], w[2][1], w[2][2],
                                     w[2][3], (ushort4*)H, 0);

    pool_k<<<NG, 256, 0, stream>>>(H, batch, fcw, fcb, out);
}

// Round 10
// 368.713 us; speedup vs baseline: 1.2930x; 1.0823x over previous
//
#include <hip/hip_runtime.h>

constexpr int NN = 100000;   // nodes
constexpr int NE = 1600000;  // edges
constexpr int DD = 64;       // channels
constexpr int NG = 256;      // graphs

constexpr int BKT_SHIFT = 8;                   // 256 nodes per bucket
constexpr int NBKT = (NN + 255) >> BKT_SHIFT;  // 391 buckets
constexpr int EPB = 4096;                      // edges per block (build kernels)
constexpr int NEB = (NE + EPB - 1) / EPB;      // 391 blocks
constexpr int CAP = 16384;                     // pair window per bucket (mean 4092)

// ---------------------------------------------------------------------------
// bf16 helpers (manual, RNE)
// ---------------------------------------------------------------------------
__device__ __forceinline__ float b2f(unsigned short u) {
    union { unsigned int u; float f; } c;
    c.u = ((unsigned int)u) << 16;
    return c.f;
}
__device__ __forceinline__ unsigned short f2b(float f) {
    union { float f; unsigned int u; } c;
    c.f = f;
    unsigned int u = c.u + 0x7fff + ((c.u >> 16) & 1);
    return (unsigned short)(u >> 16);
}
__device__ __forceinline__ float lo16(unsigned int u) {
    union { unsigned int u; float f; } c;
    c.u = u << 16;
    return c.f;
}
__device__ __forceinline__ float hi16(unsigned int u) {
    union { unsigned int u; float f; } c;
    c.u = u & 0xffff0000u;
    return c.f;
}
__device__ __forceinline__ unsigned int pk(float a, float b) {
    return ((unsigned int)f2b(a)) | (((unsigned int)f2b(b)) << 16);
}

// ---------------------------------------------------------------------------
// CSR build. pscat: ONE global pass — stage packed edges + bucket id in LDS,
// histogram, reserve windows, scatter from LDS.
// pairs packed: src (17 bits) | local-dst (8 bits) << 17.
// ---------------------------------------------------------------------------
__global__ __launch_bounds__(256) void pscat_k(const int* __restrict__ ei,
                                               int* __restrict__ gcnt,
                                               int* __restrict__ pairs) {
    __shared__ int lc[NBKT];
    __shared__ int gb[NBKT];
    __shared__ int pe[EPB];
    __shared__ unsigned short pb[EPB];
    int tid = threadIdx.x;
    for (int i = tid; i < NBKT; i += 256) lc[i] = 0;
    __syncthreads();
    int base = blockIdx.x * EPB;
    int n = min(base + EPB, NE) - base;
    for (int t = tid; t < n; t += 256) {
        int src = ei[base + t];
        int dst = ei[NE + base + t];
        int b = dst >> BKT_SHIFT;
        pe[t] = src | ((dst & 255) << 17);
        pb[t] = (unsigned short)b;
        atomicAdd(&lc[b], 1);
    }
    __syncthreads();
    for (int i = tid; i < NBKT; i += 256) {
        int c = lc[i];
        gb[i] = c ? atomicAdd(&gcnt[i], c) : 0;  // reserve exclusive window
    }
    __syncthreads();
    for (int i = tid; i < NBKT; i += 256) lc[i] = 0;  // reuse as cursor
    __syncthreads();
    for (int t = tid; t < n; t += 256) {
        int b = pb[t];
        int pos = gb[b] + atomicAdd(&lc[b], 1);
        if (pos < CAP) pairs[(size_t)b * CAP + pos] = pe[t];
    }
}

__global__ __launch_bounds__(512) void bscan_k(const int* __restrict__ gcnt,
                                               int* __restrict__ bbase) {
    __shared__ int sh[512];
    int t = threadIdx.x;
    int v = (t < NBKT) ? min(gcnt[t], CAP) : 0;
    sh[t] = v;
    __syncthreads();
    for (int off = 1; off < 512; off <<= 1) {
        int u = (t >= off) ? sh[t - off] : 0;
        __syncthreads();
        sh[t] += u;
        __syncthreads();
    }
    if (t < NBKT) bbase[t] = sh[t] - v;
}

__global__ __launch_bounds__(256) void bfill_k(const int* __restrict__ pairs,
                                               const int* __restrict__ bbase,
                                               const int* __restrict__ gcnt,
                                               int* __restrict__ rowptr,
                                               int* __restrict__ csr_src) {
    __shared__ int ldeg[256];
    __shared__ int sh[256];
    __shared__ int lcur[256];
    int b = blockIdx.x;
    int t = threadIdx.x;
    int pcnt = min(gcnt[b], CAP);
    const int* pw = pairs + (size_t)b * CAP;
    int cbeg = bbase[b];
    ldeg[t] = 0;
    __syncthreads();
    for (int i = t; i < pcnt; i += 256)
        atomicAdd(&ldeg[(pw[i] >> 17) & 255], 1);
    __syncthreads();
    int v = ldeg[t];
    sh[t] = v;
    __syncthreads();
    for (int off = 1; off < 256; off <<= 1) {
        int u = (t >= off) ? sh[t - off] : 0;
        __syncthreads();
        sh[t] += u;
        __syncthreads();
    }
    int lexcl = sh[t] - v;
    int node = (b << BKT_SHIFT) + t;
    if (node < NN) {
        rowptr[node] = cbeg + lexcl;
        if (node == NN - 1) rowptr[NN] = cbeg + lexcl + v;
    }
    lcur[t] = lexcl;
    __syncthreads();
    for (int i = t; i < pcnt; i += 256) {
        int p = pw[i];
        int pos = atomicAdd(&lcur[(p >> 17) & 255], 1);
        csr_src[cbeg + pos] = p & 0x1FFFF;
    }
}

// ---------------------------------------------------------------------------
// x (fp32) -> bf16.
// ---------------------------------------------------------------------------
__global__ __launch_bounds__(256) void xconv_k(const float* __restrict__ x,
                                               unsigned short* __restrict__ xb) {
    int i = blockIdx.x * 256 + threadIdx.x;  // float4 groups, NN*16 total
    if (i < NN * 16) {
        float4 v = reinterpret_cast<const float4*>(x)[i];
        ushort4 o;
        o.x = f2b(v.x); o.y = f2b(v.y); o.z = f2b(v.z); o.w = f2b(v.w);
        reinterpret_cast<ushort4*>(xb)[i] = o;
    }
}

// ---------------------------------------------------------------------------
// Gather + self term -> z (bf16). EIGHT nodes per wave: 8 lanes cover one
// 128 B row (16 B/lane), each lane serially accumulates ALL its node's edges
// for its own 8 channels -> NO cross-lane reduction. Indices prefetched in
// batches of 8 by the group's lanes, broadcast via __shfl (group-uniform
// control flow). 2-stage load pipeline keeps row loads independent.
// ---------------------------------------------------------------------------
__global__ __launch_bounds__(256) void gather_k(const uint4* __restrict__ hb4,
                                                const float4* __restrict__ selff,
                                                const int* __restrict__ rowptr,
                                                const int* __restrict__ csr_src,
                                                uint4* __restrict__ zb4) {
    int lane = threadIdx.x & 63;
    int nl = lane >> 3;  // node slot within wave (0..7)
    int c = lane & 7;    // 16 B chunk within row (0..7)
    int node = blockIdx.x * 32 + (threadIdx.x >> 6) * 8 + nl;
    bool valid = node < NN;
    int beg = 0, deg = 0;
    if (valid) {
        beg = rowptr[node];
        deg = rowptr[node + 1] - beg;
    }
    float a0 = 0, a1 = 0, a2 = 0, a3 = 0, a4 = 0, a5 = 0, a6 = 0, a7 = 0;
    int nb = (deg + 7) >> 3;
    int idx = (c < deg) ? csr_src[beg + c] : 0;  // this lane's slot, batch 0
    int gbase = nl << 3;
    for (int b = 0; b < nb; ++b) {
        int nj = ((b + 1) << 3) + c;
        int nextIdx = (b + 1 < nb && nj < deg) ? csr_src[beg + nj] : 0;  // prefetch
        int cnt = min(8, deg - (b << 3));
        int s0 = __shfl(idx, gbase, 64);
        uint4 v0 = hb4[s0 * 8 + c];
        for (int e = 1; e < cnt; ++e) {
            int s1 = __shfl(idx, gbase + e, 64);
            uint4 v1 = hb4[s1 * 8 + c];  // issue before consuming v0
            a0 += lo16(v0.x); a1 += hi16(v0.x);
            a2 += lo16(v0.y); a3 += hi16(v0.y);
            a4 += lo16(v0.z); a5 += hi16(v0.z);
            a6 += lo16(v0.w); a7 += hi16(v0.w);
            v0 = v1;
        }
        a0 += lo16(v0.x); a1 += hi16(v0.x);
        a2 += lo16(v0.y); a3 += hi16(v0.y);
        a4 += lo16(v0.z); a5 += hi16(v0.z);
        a6 += lo16(v0.w); a7 += hi16(v0.w);
        idx = nextIdx;
    }
    if (valid) {
        if (selff) {
            float4 s0 = selff[(size_t)node * 16 + 2 * c];
            float4 s1 = selff[(size_t)node * 16 + 2 * c + 1];
            a0 += s0.x; a1 += s0.y; a2 += s0.z; a3 += s0.w;
            a4 += s1.x; a5 += s1.y; a6 += s1.z; a7 += s1.w;
        } else {
            uint4 sv = hb4[node * 8 + c];
            a0 += lo16(sv.x); a1 += hi16(sv.x);
            a2 += lo16(sv.y); a3 += hi16(sv.y);
            a4 += lo16(sv.z); a5 += hi16(sv.z);
            a6 += lo16(sv.w); a7 += hi16(sv.w);
        }
        uint4 o;
        o.x = pk(a0, a1); o.y = pk(a2, a3); o.z = pk(a4, a5); o.w = pk(a6, a7);
        zb4[node * 8 + c] = o;
    }
}

// ---------------------------------------------------------------------------
// 2-layer MLP on bf16 z -> bf16 h, register-blocked LDS-tiled GEMM.
// ---------------------------------------------------------------------------
constexpr int ZS = 68;

__global__ __launch_bounds__(256) void mlp_k(const uint4* __restrict__ zb4,
                                             const float* __restrict__ w1,
                                             const float* __restrict__ b1,
                                             const float* __restrict__ w2,
                                             const float* __restrict__ b2,
                                             ushort4* __restrict__ houtb,
                                             int relu_out) {
    __shared__ float zT[64 * ZS];   // [k][r]
    __shared__ float wsm[64 * 64];  // [k][j]
    int tid = threadIdx.x;
    int base = blockIdx.x * 64;

    // ---- stage z (bf16) transposed into zT (fp32) ----
    {
        int r = tid >> 2;    // 0..63
        int part = tid & 3;  // 0..3
        int row = base + r;
#pragma unroll
        for (int h = 0; h < 2; ++h) {
            int cc = part + 4 * h;  // uint4 chunk 0..7
            uint4 v = make_uint4(0, 0, 0, 0);
            if (row < NN) v = zb4[(size_t)row * 8 + cc];
            int ch = cc * 8;
            zT[(ch + 0) * ZS + r] = lo16(v.x);
            zT[(ch + 1) * ZS + r] = hi16(v.x);
            zT[(ch + 2) * ZS + r] = lo16(v.y);
            zT[(ch + 3) * ZS + r] = hi16(v.y);
            zT[(ch + 4) * ZS + r] = lo16(v.z);
            zT[(ch + 5) * ZS + r] = hi16(v.z);
            zT[(ch + 6) * ZS + r] = lo16(v.w);
            zT[(ch + 7) * ZS + r] = hi16(v.w);
        }
    }
    // ---- stage w1 ----
    {
        const float4* w4 = reinterpret_cast<const float4*>(w1);
        float4* s4 = reinterpret_cast<float4*>(wsm);
        for (int i = tid; i < 1024; i += 256) s4[i] = w4[i];
    }
    __syncthreads();

    int tr = tid & 15;  // rows 4tr..4tr+3
    int tc = tid >> 4;  // cols 4tc..4tc+3

    // ---- layer 1 ----
    float4 bv = reinterpret_cast<const float4*>(b1)[tc];
    float acc[4][4];
#pragma unroll
    for (int rr = 0; rr < 4; ++rr) {
        acc[rr][0] = bv.x; acc[rr][1] = bv.y; acc[rr][2] = bv.z; acc[rr][3] = bv.w;
    }
#pragma unroll 8
    for (int k = 0; k < 64; ++k) {
        float4 zv = *reinterpret_cast<const float4*>(&zT[k * ZS + 4 * tr]);
        float4 wv = *reinterpret_cast<const float4*>(&wsm[k * 64 + 4 * tc]);
        const float zr[4] = {zv.x, zv.y, zv.z, zv.w};
        const float wc[4] = {wv.x, wv.y, wv.z, wv.w};
#pragma unroll
        for (int rr = 0; rr < 4; ++rr)
#pragma unroll
            for (int jj = 0; jj < 4; ++jj)
                acc[rr][jj] = fmaf(zr[rr], wc[jj], acc[rr][jj]);
    }
    __syncthreads();

    // ---- h1 = ReLU(acc) transposed back into zT; stage w2 ----
#pragma unroll
    for (int jj = 0; jj < 4; ++jj) {
        float4 hv;
        hv.x = fmaxf(acc[0][jj], 0.f);
        hv.y = fmaxf(acc[1][jj], 0.f);
        hv.z = fmaxf(acc[2][jj], 0.f);
        hv.w = fmaxf(acc[3][jj], 0.f);
        *reinterpret_cast<float4*>(&zT[(4 * tc + jj) * ZS + 4 * tr]) = hv;
    }
    {
        const float4* w4 = reinterpret_cast<const float4*>(w2);
        float4* s4 = reinterpret_cast<float4*>(wsm);
        for (int i = tid; i < 1024; i += 256) s4[i] = w4[i];
    }
    __syncthreads();

    // ---- layer 2 ----
    bv = reinterpret_cast<const float4*>(b2)[tc];
#pragma unroll
    for (int rr = 0; rr < 4; ++rr) {
        acc[rr][0] = bv.x; acc[rr][1] = bv.y; acc[rr][2] = bv.z; acc[rr][3] = bv.w;
    }
#pragma unroll 8
    for (int k = 0; k < 64; ++k) {
        float4 zv = *reinterpret_cast<const float4*>(&zT[k * ZS + 4 * tr]);
        float4 wv = *reinterpret_cast<const float4*>(&wsm[k * 64 + 4 * tc]);
        const float zr[4] = {zv.x, zv.y, zv.z, zv.w};
        const float wc[4] = {wv.x, wv.y, wv.z, wv.w};
#pragma unroll
        for (int rr = 0; rr < 4; ++rr)
#pragma unroll
            for (int jj = 0; jj < 4; ++jj)
                acc[rr][jj] = fmaf(zr[rr], wc[jj], acc[rr][jj]);
    }

    // ---- store bf16 ----
#pragma unroll
    for (int rr = 0; rr < 4; ++rr) {
        int row = base + 4 * tr + rr;
        if (row < NN) {
            float ox = acc[rr][0], oy = acc[rr][1], oz = acc[rr][2], ow = acc[rr][3];
            if (relu_out) {
                ox = fmaxf(ox, 0.f); oy = fmaxf(oy, 0.f);
                oz = fmaxf(oz, 0.f); ow = fmaxf(ow, 0.f);
            }
            ushort4 o;
            o.x = f2b(ox); o.y = f2b(oy); o.z = f2b(oz); o.w = f2b(ow);
            houtb[(size_t)row * 16 + tc] = o;
        }
    }
}

// ---------------------------------------------------------------------------
// Pool + FC over bf16 h: one block per graph; batch sorted -> binary search.
// ---------------------------------------------------------------------------
__device__ __forceinline__ int lower_bound_i(const int* __restrict__ a, int n, int v) {
    int lo = 0, hi = n;
    while (lo < hi) {
        int mid = (lo + hi) >> 1;
        if (a[mid] < v) lo = mid + 1; else hi = mid;
    }
    return lo;
}

__global__ __launch_bounds__(256) void pool_k(const unsigned short* __restrict__ hb,
                                              const int* __restrict__ batch,
                                              const float* __restrict__ fcw,
                                              const float* __restrict__ fcb,
                                              float* __restrict__ out) {
    int g = blockIdx.x;
    int lane = threadIdx.x & 63;
    int wv = threadIdx.x >> 6;
    int lo = lower_bound_i(batch, NN, g);
    int hi = lower_bound_i(batch, NN, g + 1);
    float w = fcw[lane];
    float sum = 0.0f;
    for (int node = lo + wv; node < hi; node += 4)
        sum += b2f(hb[(size_t)node * 64 + lane]) * w;
#pragma unroll
    for (int off = 32; off > 0; off >>= 1) sum += __shfl_down(sum, off, 64);
    __shared__ float ws[4];
    if (lane == 0) ws[wv] = sum;
    __syncthreads();
    if (threadIdx.x == 0) out[g] = ws[0] + ws[1] + ws[2] + ws[3] + fcb[0];
}

extern "C" void kernel_launch(void* const* d_in, const int* in_sizes, int n_in,
                              void* d_out, int out_size, void* d_ws, size_t ws_size,
                              hipStream_t stream) {
    const float* x = (const float*)d_in[0];
    const int* ei = (const int*)d_in[1];     // [2, E] flat: src = ei[e], dst = ei[E+e]
    const int* batch = (const int*)d_in[2];  // [N], sorted
    const float* w[3][4];
    for (int l = 0; l < 3; ++l)
        for (int i = 0; i < 4; ++i) w[l][i] = (const float*)d_in[3 + l * 4 + i];
    const float* fcw = (const float*)d_in[15];
    const float* fcb = (const float*)d_in[16];
    float* out = (float*)d_out;

    // workspace layout (~45 MB)
    int* pairs = (int*)d_ws;                               // NBKT*CAP ints (25.6 MB)
    unsigned short* Z = (unsigned short*)d_ws;             // bf16 z, aliases pairs
    unsigned short* H = (unsigned short*)((char*)d_ws + (size_t)NBKT * CAP * 4);  // bf16 h (12.8 MB)
    int* rowptr = (int*)(H + (size_t)NN * DD);             // N+1
    int* csr_src = rowptr + NN + 1;                        // NE (6.4 MB)
    int* gcnt = csr_src + NE;                              // NBKT
    int* bbase = gcnt + NBKT;                              // NBKT

    // Build CSR; pairs consumed by bfill before Z is first written.
    hipMemsetAsync(gcnt, 0, NBKT * sizeof(int), stream);
    pscat_k<<<NEB, 256, 0, stream>>>(ei, gcnt, pairs);
    bscan_k<<<1, 512, 0, stream>>>(gcnt, bbase);
    bfill_k<<<NBKT, 256, 0, stream>>>(pairs, bbase, gcnt, rowptr, csr_src);

    // x -> bf16 H
    xconv_k<<<(NN * 16 + 255) / 256, 256, 0, stream>>>(x, H);

    dim3 ggrid((NN + 31) / 32), mgrid((NN + 63) / 64);
    // L0: gather(H=xb, self=x fp32) -> Z; mlp(Z) -> H (relu)
    gather_k<<<ggrid, 256, 0, stream>>>((const uint4*)H, (const float4*)x, rowptr,
                                        csr_src, (uint4*)Z);
    mlp_k<<<mgrid, 256, 0, stream>>>((const uint4*)Z, w[0][0], w[0][1], w[0][2],
                                     w[0][3], (ushort4*)H, 1);
    // L1
    gather_k<<<ggrid, 256, 0, stream>>>((const uint4*)H, nullptr, rowptr, csr_src,
                                        (uint4*)Z);
    mlp_k<<<mgrid, 256, 0, stream>>>((const uint4*)Z, w[1][0], w[1][1], w[1][2],
                                     w[1][3], (ushort4*)H, 1);
    // L2 (no relu)
    gather_k<<<ggrid, 256, 0, stream>>>((const uint4*)H, nullptr, rowptr, csr_src,
                                        (uint4*)Z);
    mlp_k<<<mgrid, 256, 0, stream>>>((const uint4*)Z, w[2][0], w[2][1], w[2][2],
                                     w[2][3], (ushort4*)H, 0);

    pool_k<<<NG, 256, 0, stream>>>(H, batch, fcw, fcb, out);
}

// Round 12
// 350.979 us; speedup vs baseline: 1.3583x; 1.0505x over previous
//
#include <hip/hip_runtime.h>

constexpr int NN = 100000;   // nodes
constexpr int NE = 1600000;  // edges
constexpr int DD = 64;       // channels
constexpr int NG = 256;      // graphs

constexpr int BKT_SHIFT = 8;                   // 256 nodes per bucket
constexpr int NBKT = (NN + 255) >> BKT_SHIFT;  // 391 buckets
constexpr int EPB = 4096;                      // edges per block (build kernels)
constexpr int NEB = (NE + EPB - 1) / EPB;      // 391 blocks
constexpr int CAP = 16384;                     // pair window per bucket (mean 4092)

using bf16x8 = __attribute__((ext_vector_type(8))) short;
using f32x4 = __attribute__((ext_vector_type(4))) float;

// ---------------------------------------------------------------------------
// bf16 helpers (manual, RNE)
// ---------------------------------------------------------------------------
__device__ __forceinline__ float b2f(unsigned short u) {
    union { unsigned int u; float f; } c;
    c.u = ((unsigned int)u) << 16;
    return c.f;
}
__device__ __forceinline__ unsigned short f2b(float f) {
    union { float f; unsigned int u; } c;
    c.f = f;
    unsigned int u = c.u + 0x7fff + ((c.u >> 16) & 1);
    return (unsigned short)(u >> 16);
}
__device__ __forceinline__ float lo16(unsigned int u) {
    union { unsigned int u; float f; } c;
    c.u = u << 16;
    return c.f;
}
__device__ __forceinline__ float hi16(unsigned int u) {
    union { unsigned int u; float f; } c;
    c.u = u & 0xffff0000u;
    return c.f;
}
__device__ __forceinline__ unsigned int pk(float a, float b) {
    return ((unsigned int)f2b(a)) | (((unsigned int)f2b(b)) << 16);
}

// ---------------------------------------------------------------------------
// CSR build (unchanged from round 10).
// ---------------------------------------------------------------------------
__global__ __launch_bounds__(256) void pscat_k(const int* __restrict__ ei,
                                               int* __restrict__ gcnt,
                                               int* __restrict__ pairs) {
    __shared__ int lc[NBKT];
    __shared__ int gb[NBKT];
    __shared__ int pe[EPB];
    __shared__ unsigned short pb[EPB];
    int tid = threadIdx.x;
    for (int i = tid; i < NBKT; i += 256) lc[i] = 0;
    __syncthreads();
    int base = blockIdx.x * EPB;
    int n = min(base + EPB, NE) - base;
    for (int t = tid; t < n; t += 256) {
        int src = ei[base + t];
        int dst = ei[NE + base + t];
        int b = dst >> BKT_SHIFT;
        pe[t] = src | ((dst & 255) << 17);
        pb[t] = (unsigned short)b;
        atomicAdd(&lc[b], 1);
    }
    __syncthreads();
    for (int i = tid; i < NBKT; i += 256) {
        int c = lc[i];
        gb[i] = c ? atomicAdd(&gcnt[i], c) : 0;
    }
    __syncthreads();
    for (int i = tid; i < NBKT; i += 256) lc[i] = 0;
    __syncthreads();
    for (int t = tid; t < n; t += 256) {
        int b = pb[t];
        int pos = gb[b] + atomicAdd(&lc[b], 1);
        if (pos < CAP) pairs[(size_t)b * CAP + pos] = pe[t];
    }
}

__global__ __launch_bounds__(512) void bscan_k(const int* __restrict__ gcnt,
                                               int* __restrict__ bbase) {
    __shared__ int sh[512];
    int t = threadIdx.x;
    int v = (t < NBKT) ? min(gcnt[t], CAP) : 0;
    sh[t] = v;
    __syncthreads();
    for (int off = 1; off < 512; off <<= 1) {
        int u = (t >= off) ? sh[t - off] : 0;
        __syncthreads();
        sh[t] += u;
        __syncthreads();
    }
    if (t < NBKT) bbase[t] = sh[t] - v;
}

__global__ __launch_bounds__(256) void bfill_k(const int* __restrict__ pairs,
                                               const int* __restrict__ bbase,
                                               const int* __restrict__ gcnt,
                                               int* __restrict__ rowptr,
                                               int* __restrict__ csr_src) {
    __shared__ int ldeg[256];
    __shared__ int sh[256];
    __shared__ int lcur[256];
    int b = blockIdx.x;
    int t = threadIdx.x;
    int pcnt = min(gcnt[b], CAP);
    const int* pw = pairs + (size_t)b * CAP;
    int cbeg = bbase[b];
    ldeg[t] = 0;
    __syncthreads();
    for (int i = t; i < pcnt; i += 256)
        atomicAdd(&ldeg[(pw[i] >> 17) & 255], 1);
    __syncthreads();
    int v = ldeg[t];
    sh[t] = v;
    __syncthreads();
    for (int off = 1; off < 256; off <<= 1) {
        int u = (t >= off) ? sh[t - off] : 0;
        __syncthreads();
        sh[t] += u;
        __syncthreads();
    }
    int lexcl = sh[t] - v;
    int node = (b << BKT_SHIFT) + t;
    if (node < NN) {
        rowptr[node] = cbeg + lexcl;
        if (node == NN - 1) rowptr[NN] = cbeg + lexcl + v;
    }
    lcur[t] = lexcl;
    __syncthreads();
    for (int i = t; i < pcnt; i += 256) {
        int p = pw[i];
        int pos = atomicAdd(&lcur[(p >> 17) & 255], 1);
        csr_src[cbeg + pos] = p & 0x1FFFF;
    }
}

// ---------------------------------------------------------------------------
// x (fp32) -> bf16.
// ---------------------------------------------------------------------------
__global__ __launch_bounds__(256) void xconv_k(const float* __restrict__ x,
                                               unsigned short* __restrict__ xb) {
    int i = blockIdx.x * 256 + threadIdx.x;
    if (i < NN * 16) {
        float4 v = reinterpret_cast<const float4*>(x)[i];
        ushort4 o;
        o.x = f2b(v.x); o.y = f2b(v.y); o.z = f2b(v.z); o.w = f2b(v.w);
        reinterpret_cast<ushort4*>(xb)[i] = o;
    }
}

// ---------------------------------------------------------------------------
// Weight prep: fp32 W[k][n] -> SPLIT bf16 (hi + residual lo) in B-fragment
// order for mfma_16x16x32_bf16:
//   frag[((kb*64 + n)*4 + quad)*8 + j] = W[kb*32 + quad*8 + j][n]
// Per matrix: hi at mat*8192, lo at mat*8192+4096. 6 matrices.
// ---------------------------------------------------------------------------
__global__ __launch_bounds__(256) void wprep_k(const float* __restrict__ w0,
                                               const float* __restrict__ w1,
                                               const float* __restrict__ w2,
                                               const float* __restrict__ w3,
                                               const float* __restrict__ w4,
                                               const float* __restrict__ w5,
                                               unsigned short* __restrict__ out) {
    const float* ws[6] = {w0, w1, w2, w3, w4, w5};
    const float* w = ws[blockIdx.x];
    unsigned short* o = out + blockIdx.x * 8192;
    for (int i = threadIdx.x; i < 4096; i += 256) {
        int j = i & 7;
        int quad = (i >> 3) & 3;
        int n = (i >> 5) & 63;
        int kb = i >> 11;
        int k = kb * 32 + quad * 8 + j;
        float wv = w[k * 64 + n];
        unsigned short hi = f2b(wv);
        // RNE can overshoot; residual captures it exactly in bf16 range
        o[i] = hi;
        o[i + 4096] = f2b(wv - b2f(hi));
    }
}

// ---------------------------------------------------------------------------
// Gather + self term -> z (bf16). Eight nodes per wave (round-10 structure).
// ---------------------------------------------------------------------------
__global__ __launch_bounds__(256) void gather_k(const uint4* __restrict__ hb4,
                                                const float4* __restrict__ selff,
                                                const int* __restrict__ rowptr,
                                                const int* __restrict__ csr_src,
                                                uint4* __restrict__ zb4) {
    int lane = threadIdx.x & 63;
    int nl = lane >> 3;  // node slot within wave (0..7)
    int c = lane & 7;    // 16 B chunk within row (0..7)
    int node = blockIdx.x * 32 + (threadIdx.x >> 6) * 8 + nl;
    bool valid = node < NN;
    int beg = 0, deg = 0;
    if (valid) {
        beg = rowptr[node];
        deg = rowptr[node + 1] - beg;
    }
    float a0 = 0, a1 = 0, a2 = 0, a3 = 0, a4 = 0, a5 = 0, a6 = 0, a7 = 0;
    int nb = (deg + 7) >> 3;
    int idx = (c < deg) ? csr_src[beg + c] : 0;
    int gbase = nl << 3;
    for (int b = 0; b < nb; ++b) {
        int nj = ((b + 1) << 3) + c;
        int nextIdx = (b + 1 < nb && nj < deg) ? csr_src[beg + nj] : 0;
        int cnt = min(8, deg - (b << 3));
        int s0 = __shfl(idx, gbase, 64);
        uint4 v0 = hb4[s0 * 8 + c];
        for (int e = 1; e < cnt; ++e) {
            int s1 = __shfl(idx, gbase + e, 64);
            uint4 v1 = hb4[s1 * 8 + c];
            a0 += lo16(v0.x); a1 += hi16(v0.x);
            a2 += lo16(v0.y); a3 += hi16(v0.y);
            a4 += lo16(v0.z); a5 += hi16(v0.z);
            a6 += lo16(v0.w); a7 += hi16(v0.w);
            v0 = v1;
        }
        a0 += lo16(v0.x); a1 += hi16(v0.x);
        a2 += lo16(v0.y); a3 += hi16(v0.y);
        a4 += lo16(v0.z); a5 += hi16(v0.z);
        a6 += lo16(v0.w); a7 += hi16(v0.w);
        idx = nextIdx;
    }
    if (valid) {
        if (selff) {
            float4 s0 = selff[(size_t)node * 16 + 2 * c];
            float4 s1 = selff[(size_t)node * 16 + 2 * c + 1];
            a0 += s0.x; a1 += s0.y; a2 += s0.z; a3 += s0.w;
            a4 += s1.x; a5 += s1.y; a6 += s1.z; a7 += s1.w;
        } else {
            uint4 sv = hb4[node * 8 + c];
            a0 += lo16(sv.x); a1 += hi16(sv.x);
            a2 += lo16(sv.y); a3 += hi16(sv.y);
            a4 += lo16(sv.z); a5 += hi16(sv.z);
            a6 += lo16(sv.w); a7 += hi16(sv.w);
        }
        uint4 o;
        o.x = pk(a0, a1); o.y = pk(a2, a3); o.z = pk(a4, a5); o.w = pk(a6, a7);
        zb4[node * 8 + c] = o;
    }
}

// ---------------------------------------------------------------------------
// 2-layer MLP via MFMA with SPLIT-bf16 precision recovery.
// Block = 256 = 4 waves; 64-row tile; wave w owns rows [w*16, w*16+16).
// GEMM1: z @ (Whi + Wlo)            -> 4 MFMA per n-tile (16/wave)
// GEMM2: (Ahi+Alo) @ (Whi+Wlo) - AloWlo -> 6 MFMA per n-tile (24/wave)
// h1 kept as hi+lo bf16 in two LDS buffers (stride 72, bank-balanced).
// C-layout: col=lane&15, row=quad*4+reg [m89/m91]; A: A[m=lane&15][quad*8+j].
// ---------------------------------------------------------------------------
__global__ __launch_bounds__(256) void mlp_k(const unsigned short* __restrict__ zb,
                                             const unsigned short* __restrict__ wf1,
                                             const float* __restrict__ b1,
                                             const unsigned short* __restrict__ wf2,
                                             const float* __restrict__ b2,
                                             unsigned short* __restrict__ houtb,
                                             int relu_out) {
    __shared__ unsigned short hlh[64 * 72];  // h1 hi
    __shared__ unsigned short hll[64 * 72];  // h1 lo
    int tid = threadIdx.x;
    int base = blockIdx.x * 64;
    int lane = tid & 63;
    int wv = tid >> 6;
    int m = lane & 15;
    int quad = lane >> 4;
    int grow = base + wv * 16 + m;
    int arow = grow < NN ? grow : NN - 1;

    // ---- GEMM1: A from global z (bf16) ----
    const bf16x8* zp = reinterpret_cast<const bf16x8*>(zb + (size_t)arow * 64);
    bf16x8 a0 = zp[quad];      // kb=0
    bf16x8 a1 = zp[4 + quad];  // kb=1
    const bf16x8* wh1 = reinterpret_cast<const bf16x8*>(wf1);
    const bf16x8* wl1 = reinterpret_cast<const bf16x8*>(wf1 + 4096);
    f32x4 acc[4];
#pragma unroll
    for (int nt = 0; nt < 4; ++nt) {
        int n = nt * 16 + m;
        bf16x8 bh0 = wh1[(0 * 64 + n) * 4 + quad];
        bf16x8 bh1 = wh1[(1 * 64 + n) * 4 + quad];
        bf16x8 bl0 = wl1[(0 * 64 + n) * 4 + quad];
        bf16x8 bl1 = wl1[(1 * 64 + n) * 4 + quad];
        f32x4 c = {0.f, 0.f, 0.f, 0.f};
        c = __builtin_amdgcn_mfma_f32_16x16x32_bf16(a0, bh0, c, 0, 0, 0);
        c = __builtin_amdgcn_mfma_f32_16x16x32_bf16(a1, bh1, c, 0, 0, 0);
        c = __builtin_amdgcn_mfma_f32_16x16x32_bf16(a0, bl0, c, 0, 0, 0);
        c = __builtin_amdgcn_mfma_f32_16x16x32_bf16(a1, bl1, c, 0, 0, 0);
        acc[nt] = c;
    }
    // ---- h1 = ReLU(acc + b1) -> split bf16 into LDS (C-layout scatter) ----
#pragma unroll
    for (int nt = 0; nt < 4; ++nt) {
        int col = nt * 16 + m;
        float bb = b1[col];
#pragma unroll
        for (int rr = 0; rr < 4; ++rr) {
            float v = fmaxf(acc[nt][rr] + bb, 0.f);
            unsigned short hi = f2b(v);
            hlh[(wv * 16 + quad * 4 + rr) * 72 + col] = hi;
            hll[(wv * 16 + quad * 4 + rr) * 72 + col] = f2b(v - b2f(hi));
        }
    }
    __syncthreads();

    // ---- GEMM2: A (hi+lo) from LDS ----
    bf16x8 ch0 = *reinterpret_cast<const bf16x8*>(&hlh[(wv * 16 + m) * 72 + quad * 8]);
    bf16x8 ch1 = *reinterpret_cast<const bf16x8*>(&hlh[(wv * 16 + m) * 72 + 32 + quad * 8]);
    bf16x8 cl0 = *reinterpret_cast<const bf16x8*>(&hll[(wv * 16 + m) * 72 + quad * 8]);
    bf16x8 cl1 = *reinterpret_cast<const bf16x8*>(&hll[(wv * 16 + m) * 72 + 32 + quad * 8]);
    const bf16x8* wh2 = reinterpret_cast<const bf16x8*>(wf2);
    const bf16x8* wl2 = reinterpret_cast<const bf16x8*>(wf2 + 4096);
#pragma unroll
    for (int nt = 0; nt < 4; ++nt) {
        int n = nt * 16 + m;
        bf16x8 bh0 = wh2[(0 * 64 + n) * 4 + quad];
        bf16x8 bh1 = wh2[(1 * 64 + n) * 4 + quad];
        bf16x8 bl0 = wl2[(0 * 64 + n) * 4 + quad];
        bf16x8 bl1 = wl2[(1 * 64 + n) * 4 + quad];
        f32x4 c = {0.f, 0.f, 0.f, 0.f};
        c = __builtin_amdgcn_mfma_f32_16x16x32_bf16(ch0, bh0, c, 0, 0, 0);
        c = __builtin_amdgcn_mfma_f32_16x16x32_bf16(ch1, bh1, c, 0, 0, 0);
        c = __builtin_amdgcn_mfma_f32_16x16x32_bf16(ch0, bl0, c, 0, 0, 0);
        c = __builtin_amdgcn_mfma_f32_16x16x32_bf16(ch1, bl1, c, 0, 0, 0);
        c = __builtin_amdgcn_mfma_f32_16x16x32_bf16(cl0, bh0, c, 0, 0, 0);
        c = __builtin_amdgcn_mfma_f32_16x16x32_bf16(cl1, bh1, c, 0, 0, 0);
        acc[nt] = c;
    }
    __syncthreads();

    // ---- epilogue: bias (+relu) -> LDS bf16, then coalesced stores ----
#pragma unroll
    for (int nt = 0; nt < 4; ++nt) {
        int col = nt * 16 + m;
        float bb = b2[col];
#pragma unroll
        for (int rr = 0; rr < 4; ++rr) {
            float v = acc[nt][rr] + bb;
            if (relu_out) v = fmaxf(v, 0.f);
            hlh[(wv * 16 + quad * 4 + rr) * 72 + col] = f2b(v);
        }
    }
    __syncthreads();
    for (int i = tid; i < 64 * 8; i += 256) {
        int row = i >> 3;
        int ch = i & 7;
        int orow = base + row;
        if (orow < NN) {
            uint4 v = *reinterpret_cast<const uint4*>(&hlh[row * 72 + ch * 8]);
            *reinterpret_cast<uint4*>(houtb + (size_t)orow * 64 + ch * 8) = v;
        }
    }
}

// ---------------------------------------------------------------------------
// Pool + FC over bf16 h (unchanged).
// ---------------------------------------------------------------------------
__device__ __forceinline__ int lower_bound_i(const int* __restrict__ a, int n, int v) {
    int lo = 0, hi = n;
    while (lo < hi) {
        int mid = (lo + hi) >> 1;
        if (a[mid] < v) lo = mid + 1; else hi = mid;
    }
    return lo;
}

__global__ __launch_bounds__(256) void pool_k(const unsigned short* __restrict__ hb,
                                              const int* __restrict__ batch,
                                              const float* __restrict__ fcw,
                                              const float* __restrict__ fcb,
                                              float* __restrict__ out) {
    int g = blockIdx.x;
    int lane = threadIdx.x & 63;
    int wv = threadIdx.x >> 6;
    int lo = lower_bound_i(batch, NN, g);
    int hi = lower_bound_i(batch, NN, g + 1);
    float w = fcw[lane];
    float sum = 0.0f;
    for (int node = lo + wv; node < hi; node += 4)
        sum += b2f(hb[(size_t)node * 64 + lane]) * w;
#pragma unroll
    for (int off = 32; off > 0; off >>= 1) sum += __shfl_down(sum, off, 64);
    __shared__ float ws[4];
    if (lane == 0) ws[wv] = sum;
    __syncthreads();
    if (threadIdx.x == 0) out[g] = ws[0] + ws[1] + ws[2] + ws[3] + fcb[0];
}

extern "C" void kernel_launch(void* const* d_in, const int* in_sizes, int n_in,
                              void* d_out, int out_size, void* d_ws, size_t ws_size,
                              hipStream_t stream) {
    const float* x = (const float*)d_in[0];
    const int* ei = (const int*)d_in[1];     // [2, E] flat
    const int* batch = (const int*)d_in[2];  // [N], sorted
    const float* w[3][4];
    for (int l = 0; l < 3; ++l)
        for (int i = 0; i < 4; ++i) w[l][i] = (const float*)d_in[3 + l * 4 + i];
    const float* fcw = (const float*)d_in[15];
    const float* fcb = (const float*)d_in[16];
    float* out = (float*)d_out;

    // workspace layout (~45 MB)
    int* pairs = (int*)d_ws;                               // NBKT*CAP ints (25.6 MB)
    unsigned short* Z = (unsigned short*)d_ws;             // bf16 z, aliases pairs
    unsigned short* H = (unsigned short*)((char*)d_ws + (size_t)NBKT * CAP * 4);  // 12.8 MB
    int* rowptr = (int*)(H + (size_t)NN * DD);             // N+1
    int* csr_src = rowptr + NN + 1;                        // NE (6.4 MB)
    int* gcnt = csr_src + NE;                              // NBKT
    int* bbase = gcnt + NBKT;                              // NBKT
    unsigned short* wf = (unsigned short*)(bbase + NBKT);  // 6*8192 bf16 (96 KB)

    // Build CSR; pairs consumed by bfill before Z is first written.
    hipMemsetAsync(gcnt, 0, NBKT * sizeof(int), stream);
    pscat_k<<<NEB, 256, 0, stream>>>(ei, gcnt, pairs);
    bscan_k<<<1, 512, 0, stream>>>(gcnt, bbase);
    bfill_k<<<NBKT, 256, 0, stream>>>(pairs, bbase, gcnt, rowptr, csr_src);

    // weights -> split bf16 MFMA B-fragment order; x -> bf16 H
    wprep_k<<<6, 256, 0, stream>>>(w[0][0], w[0][2], w[1][0], w[1][2], w[2][0],
                                   w[2][2], wf);
    xconv_k<<<(NN * 16 + 255) / 256, 256, 0, stream>>>(x, H);

    dim3 ggrid((NN + 31) / 32), mgrid((NN + 63) / 64);
    // L0
    gather_k<<<ggrid, 256, 0, stream>>>((const uint4*)H, (const float4*)x, rowptr,
                                        csr_src, (uint4*)Z);
    mlp_k<<<mgrid, 256, 0, stream>>>(Z, wf + 0 * 8192, w[0][1], wf + 1 * 8192,
                                     w[0][3], H, 1);
    // L1
    gather_k<<<ggrid, 256, 0, stream>>>((const uint4*)H, nullptr, rowptr, csr_src,
                                        (uint4*)Z);
    mlp_k<<<mgrid, 256, 0, stream>>>(Z, wf + 2 * 8192, w[1][1], wf + 3 * 8192,
                                     w[1][3], H, 1);
    // L2 (no relu)
    gather_k<<<ggrid, 256, 0, stream>>>((const uint4*)H, nullptr, rowptr, csr_src,
                                        (uint4*)Z);
    mlp_k<<<mgrid, 256, 0, stream>>>(Z, wf + 4 * 8192, w[2][1], wf + 5 * 8192,
                                     w[2][3], H, 0);

    pool_k<<<NG, 256, 0, stream>>>(H, batch, fcw, fcb, out);
}

// Round 13
// 305.671 us; speedup vs baseline: 1.5596x; 1.1482x over previous
//
#include <hip/hip_runtime.h>

constexpr int NN = 100000;   // nodes
constexpr int NE = 1600000;  // edges
constexpr int DD = 64;       // channels
constexpr int NG = 256;      // graphs

constexpr int BKT_SHIFT = 8;                   // 256 nodes per bucket
constexpr int NBKT = (NN + 255) >> BKT_SHIFT;  // 391 buckets
constexpr int EPB = 4096;                      // edges per block (build kernels)
constexpr int NEB = (NE + EPB - 1) / EPB;      // 391 blocks
constexpr int CAP = 16384;                     // pair window per bucket (mean 4092)

using bf16x8 = __attribute__((ext_vector_type(8))) short;
using f32x4 = __attribute__((ext_vector_type(4))) float;

// ---------------------------------------------------------------------------
// bf16 helpers (manual, RNE)
// ---------------------------------------------------------------------------
__device__ __forceinline__ float b2f(unsigned short u) {
    union { unsigned int u; float f; } c;
    c.u = ((unsigned int)u) << 16;
    return c.f;
}
__device__ __forceinline__ unsigned short f2b(float f) {
    union { float f; unsigned int u; } c;
    c.f = f;
    unsigned int u = c.u + 0x7fff + ((c.u >> 16) & 1);
    return (unsigned short)(u >> 16);
}
__device__ __forceinline__ float lo16(unsigned int u) {
    union { unsigned int u; float f; } c;
    c.u = u << 16;
    return c.f;
}
__device__ __forceinline__ float hi16(unsigned int u) {
    union { unsigned int u; float f; } c;
    c.u = u & 0xffff0000u;
    return c.f;
}
__device__ __forceinline__ unsigned int pk(float a, float b) {
    return ((unsigned int)f2b(a)) | (((unsigned int)f2b(b)) << 16);
}

// ---------------------------------------------------------------------------
// prep_k: fused one-time prep.
//   blocks 0..5   : weight -> split bf16 (hi + residual lo), B-frag order
//   block  6      : out[g] = fcb; gcnt = 0
//   blocks 7..    : x (fp32) -> bf16
// ---------------------------------------------------------------------------
__global__ __launch_bounds__(256) void prep_k(const float* __restrict__ w0,
                                              const float* __restrict__ w1,
                                              const float* __restrict__ w2,
                                              const float* __restrict__ w3,
                                              const float* __restrict__ w4,
                                              const float* __restrict__ w5,
                                              unsigned short* __restrict__ wf,
                                              const float* __restrict__ x,
                                              unsigned short* __restrict__ xb,
                                              int* __restrict__ gcnt,
                                              const float* __restrict__ fcb,
                                              float* __restrict__ outp) {
    int bid = blockIdx.x;
    int tid = threadIdx.x;
    if (bid < 6) {
        const float* ws[6] = {w0, w1, w2, w3, w4, w5};
        const float* w = ws[bid];
        unsigned short* o = wf + bid * 8192;
        for (int i = tid; i < 4096; i += 256) {
            int j = i & 7;
            int quad = (i >> 3) & 3;
            int n = (i >> 5) & 63;
            int kb = i >> 11;
            int k = kb * 32 + quad * 8 + j;
            float wv = w[k * 64 + n];
            unsigned short hi = f2b(wv);
            o[i] = hi;
            o[i + 4096] = f2b(wv - b2f(hi));
        }
    } else if (bid == 6) {
        if (tid < NG) outp[tid] = fcb[0];
        for (int i = tid; i < NBKT; i += 256) gcnt[i] = 0;
    } else {
        int i = (bid - 7) * 256 + tid;
        if (i < NN * 16) {
            float4 v = reinterpret_cast<const float4*>(x)[i];
            ushort4 o;
            o.x = f2b(v.x); o.y = f2b(v.y); o.z = f2b(v.z); o.w = f2b(v.w);
            reinterpret_cast<ushort4*>(xb)[i] = o;
        }
    }
}

// ---------------------------------------------------------------------------
// pscat: edges -> bucket-major packed pairs (one global pass, LDS staged).
// pairs packed: src (17 bits) | local-dst (8 bits) << 17.
// ---------------------------------------------------------------------------
__global__ __launch_bounds__(256) void pscat_k(const int* __restrict__ ei,
                                               int* __restrict__ gcnt,
                                               int* __restrict__ pairs) {
    __shared__ int lc[NBKT];
    __shared__ int gb[NBKT];
    __shared__ int pe[EPB];
    __shared__ unsigned short pb[EPB];
    int tid = threadIdx.x;
    for (int i = tid; i < NBKT; i += 256) lc[i] = 0;
    __syncthreads();
    int base = blockIdx.x * EPB;
    int n = min(base + EPB, NE) - base;
    for (int t = tid; t < n; t += 256) {
        int src = ei[base + t];
        int dst = ei[NE + base + t];
        int b = dst >> BKT_SHIFT;
        pe[t] = src | ((dst & 255) << 17);
        pb[t] = (unsigned short)b;
        atomicAdd(&lc[b], 1);
    }
    __syncthreads();
    for (int i = tid; i < NBKT; i += 256) {
        int c = lc[i];
        gb[i] = c ? atomicAdd(&gcnt[i], c) : 0;
    }
    __syncthreads();
    for (int i = tid; i < NBKT; i += 256) lc[i] = 0;
    __syncthreads();
    for (int t = tid; t < n; t += 256) {
        int b = pb[t];
        int pos = gb[b] + atomicAdd(&lc[b], 1);
        if (pos < CAP) pairs[(size_t)b * CAP + pos] = pe[t];
    }
}

// ---------------------------------------------------------------------------
// bfill: bucket pairs -> rowptr + csr_src. Prefix (bucket base) computed
// in-kernel per block (391-element reduce over gcnt) — no separate scan.
// ---------------------------------------------------------------------------
__global__ __launch_bounds__(256) void bfill_k(const int* __restrict__ pairs,
                                               const int* __restrict__ gcnt,
                                               int* __restrict__ rowptr,
                                               int* __restrict__ csr_src) {
    __shared__ int ldeg[256];
    __shared__ int sh[256];
    __shared__ int lcur[256];
    __shared__ int redsh[4];
    int b = blockIdx.x;
    int t = threadIdx.x;
    // cbeg = sum_{i<b} min(gcnt[i], CAP)
    int part = 0;
    for (int i = t; i < NBKT; i += 256)
        if (i < b) part += min(gcnt[i], CAP);
#pragma unroll
    for (int off = 32; off > 0; off >>= 1) part += __shfl_down(part, off, 64);
    if ((t & 63) == 0) redsh[t >> 6] = part;
    ldeg[t] = 0;
    __syncthreads();
    int cbeg = redsh[0] + redsh[1] + redsh[2] + redsh[3];
    int pcnt = min(gcnt[b], CAP);
    const int* pw = pairs + (size_t)b * CAP;
    for (int i = t; i < pcnt; i += 256)
        atomicAdd(&ldeg[(pw[i] >> 17) & 255], 1);
    __syncthreads();
    int v = ldeg[t];
    sh[t] = v;
    __syncthreads();
    for (int off = 1; off < 256; off <<= 1) {
        int u = (t >= off) ? sh[t - off] : 0;
        __syncthreads();
        sh[t] += u;
        __syncthreads();
    }
    int lexcl = sh[t] - v;
    int node = (b << BKT_SHIFT) + t;
    if (node < NN) {
        rowptr[node] = cbeg + lexcl;
        if (node == NN - 1) rowptr[NN] = cbeg + lexcl + v;
    }
    lcur[t] = lexcl;
    __syncthreads();
    for (int i = t; i < pcnt; i += 256) {
        int p = pw[i];
        int pos = atomicAdd(&lcur[(p >> 17) & 255], 1);
        csr_src[cbeg + pos] = p & 0x1FFFF;
    }
}

// ---------------------------------------------------------------------------
// Gather + self term -> z (bf16). Eight nodes per wave (round-10 structure).
// ---------------------------------------------------------------------------
__global__ __launch_bounds__(256) void gather_k(const uint4* __restrict__ hb4,
                                                const float4* __restrict__ selff,
                                                const int* __restrict__ rowptr,
                                                const int* __restrict__ csr_src,
                                                uint4* __restrict__ zb4) {
    int lane = threadIdx.x & 63;
    int nl = lane >> 3;  // node slot within wave (0..7)
    int c = lane & 7;    // 16 B chunk within row (0..7)
    int node = blockIdx.x * 32 + (threadIdx.x >> 6) * 8 + nl;
    bool valid = node < NN;
    int beg = 0, deg = 0;
    if (valid) {
        beg = rowptr[node];
        deg = rowptr[node + 1] - beg;
    }
    float a0 = 0, a1 = 0, a2 = 0, a3 = 0, a4 = 0, a5 = 0, a6 = 0, a7 = 0;
    int nb = (deg + 7) >> 3;
    int idx = (c < deg) ? csr_src[beg + c] : 0;
    int gbase = nl << 3;
    for (int b = 0; b < nb; ++b) {
        int nj = ((b + 1) << 3) + c;
        int nextIdx = (b + 1 < nb && nj < deg) ? csr_src[beg + nj] : 0;
        int cnt = min(8, deg - (b << 3));
        int s0 = __shfl(idx, gbase, 64);
        uint4 v0 = hb4[s0 * 8 + c];
        for (int e = 1; e < cnt; ++e) {
            int s1 = __shfl(idx, gbase + e, 64);
            uint4 v1 = hb4[s1 * 8 + c];
            a0 += lo16(v0.x); a1 += hi16(v0.x);
            a2 += lo16(v0.y); a3 += hi16(v0.y);
            a4 += lo16(v0.z); a5 += hi16(v0.z);
            a6 += lo16(v0.w); a7 += hi16(v0.w);
            v0 = v1;
        }
        a0 += lo16(v0.x); a1 += hi16(v0.x);
        a2 += lo16(v0.y); a3 += hi16(v0.y);
        a4 += lo16(v0.z); a5 += hi16(v0.z);
        a6 += lo16(v0.w); a7 += hi16(v0.w);
        idx = nextIdx;
    }
    if (valid) {
        if (selff) {
            float4 s0 = selff[(size_t)node * 16 + 2 * c];
            float4 s1 = selff[(size_t)node * 16 + 2 * c + 1];
            a0 += s0.x; a1 += s0.y; a2 += s0.z; a3 += s0.w;
            a4 += s1.x; a5 += s1.y; a6 += s1.z; a7 += s1.w;
        } else {
            uint4 sv = hb4[node * 8 + c];
            a0 += lo16(sv.x); a1 += hi16(sv.x);
            a2 += lo16(sv.y); a3 += hi16(sv.y);
            a4 += lo16(sv.z); a5 += hi16(sv.z);
            a6 += lo16(sv.w); a7 += hi16(sv.w);
        }
        uint4 o;
        o.x = pk(a0, a1); o.y = pk(a2, a3); o.z = pk(a4, a5); o.w = pk(a6, a7);
        zb4[node * 8 + c] = o;
    }
}

// ---------------------------------------------------------------------------
// 2-layer MLP via MFMA with split-bf16 precision recovery (round-12) plus
// optional fused global_add_pool + FC (pool_mode, last layer):
// per-thread dot of C-frag with fcw, 4-step shuffle reduce over the 16
// m-lanes, LDS per-graph accumulate (batch sorted -> ~2 graphs/block),
// few global atomics/block; H store skipped.
// ---------------------------------------------------------------------------
__global__ __launch_bounds__(256) void mlp_k(const unsigned short* __restrict__ zb,
                                             const unsigned short* __restrict__ wf1,
                                             const float* __restrict__ b1,
                                             const unsigned short* __restrict__ wf2,
                                             const float* __restrict__ b2,
                                             unsigned short* __restrict__ houtb,
                                             int relu_out, int pool_mode,
                                             const int* __restrict__ batch,
                                             const float* __restrict__ fcw,
                                             float* __restrict__ outp) {
    __shared__ unsigned short hlh[64 * 72];  // h1 hi
    __shared__ unsigned short hll[64 * 72];  // h1 lo
    int tid = threadIdx.x;
    int base = blockIdx.x * 64;
    int lane = tid & 63;
    int wv = tid >> 6;
    int m = lane & 15;
    int quad = lane >> 4;
    int grow = base + wv * 16 + m;
    int arow = grow < NN ? grow : NN - 1;

    // ---- GEMM1: A from global z (bf16) ----
    const bf16x8* zp = reinterpret_cast<const bf16x8*>(zb + (size_t)arow * 64);
    bf16x8 a0 = zp[quad];      // kb=0
    bf16x8 a1 = zp[4 + quad];  // kb=1
    const bf16x8* wh1 = reinterpret_cast<const bf16x8*>(wf1);
    const bf16x8* wl1 = reinterpret_cast<const bf16x8*>(wf1 + 4096);
    f32x4 acc[4];
#pragma unroll
    for (int nt = 0; nt < 4; ++nt) {
        int n = nt * 16 + m;
        bf16x8 bh0 = wh1[(0 * 64 + n) * 4 + quad];
        bf16x8 bh1 = wh1[(1 * 64 + n) * 4 + quad];
        bf16x8 bl0 = wl1[(0 * 64 + n) * 4 + quad];
        bf16x8 bl1 = wl1[(1 * 64 + n) * 4 + quad];
        f32x4 c = {0.f, 0.f, 0.f, 0.f};
        c = __builtin_amdgcn_mfma_f32_16x16x32_bf16(a0, bh0, c, 0, 0, 0);
        c = __builtin_amdgcn_mfma_f32_16x16x32_bf16(a1, bh1, c, 0, 0, 0);
        c = __builtin_amdgcn_mfma_f32_16x16x32_bf16(a0, bl0, c, 0, 0, 0);
        c = __builtin_amdgcn_mfma_f32_16x16x32_bf16(a1, bl1, c, 0, 0, 0);
        acc[nt] = c;
    }
    // ---- h1 = ReLU(acc + b1) -> split bf16 into LDS (C-layout scatter) ----
#pragma unroll
    for (int nt = 0; nt < 4; ++nt) {
        int col = nt * 16 + m;
        float bb = b1[col];
#pragma unroll
        for (int rr = 0; rr < 4; ++rr) {
            float v = fmaxf(acc[nt][rr] + bb, 0.f);
            unsigned short hi = f2b(v);
            hlh[(wv * 16 + quad * 4 + rr) * 72 + col] = hi;
            hll[(wv * 16 + quad * 4 + rr) * 72 + col] = f2b(v - b2f(hi));
        }
    }
    __syncthreads();

    // ---- GEMM2: A (hi+lo) from LDS ----
    bf16x8 ch0 = *reinterpret_cast<const bf16x8*>(&hlh[(wv * 16 + m) * 72 + quad * 8]);
    bf16x8 ch1 = *reinterpret_cast<const bf16x8*>(&hlh[(wv * 16 + m) * 72 + 32 + quad * 8]);
    bf16x8 cl0 = *reinterpret_cast<const bf16x8*>(&hll[(wv * 16 + m) * 72 + quad * 8]);
    bf16x8 cl1 = *reinterpret_cast<const bf16x8*>(&hll[(wv * 16 + m) * 72 + 32 + quad * 8]);
    const bf16x8* wh2 = reinterpret_cast<const bf16x8*>(wf2);
    const bf16x8* wl2 = reinterpret_cast<const bf16x8*>(wf2 + 4096);
#pragma unroll
    for (int nt = 0; nt < 4; ++nt) {
        int n = nt * 16 + m;
        bf16x8 bh0 = wh2[(0 * 64 + n) * 4 + quad];
        bf16x8 bh1 = wh2[(1 * 64 + n) * 4 + quad];
        bf16x8 bl0 = wl2[(0 * 64 + n) * 4 + quad];
        bf16x8 bl1 = wl2[(1 * 64 + n) * 4 + quad];
        f32x4 c = {0.f, 0.f, 0.f, 0.f};
        c = __builtin_amdgcn_mfma_f32_16x16x32_bf16(ch0, bh0, c, 0, 0, 0);
        c = __builtin_amdgcn_mfma_f32_16x16x32_bf16(ch1, bh1, c, 0, 0, 0);
        c = __builtin_amdgcn_mfma_f32_16x16x32_bf16(ch0, bl0, c, 0, 0, 0);
        c = __builtin_amdgcn_mfma_f32_16x16x32_bf16(ch1, bl1, c, 0, 0, 0);
        c = __builtin_amdgcn_mfma_f32_16x16x32_bf16(cl0, bh0, c, 0, 0, 0);
        c = __builtin_amdgcn_mfma_f32_16x16x32_bf16(cl1, bh1, c, 0, 0, 0);
        acc[nt] = c;
    }
    __syncthreads();

    if (pool_mode) {
        // ---- fused global_add_pool + FC ----
        float psum[4] = {0.f, 0.f, 0.f, 0.f};
#pragma unroll
        for (int nt = 0; nt < 4; ++nt) {
            int col = nt * 16 + m;
            float fw = fcw[col];
            float bb = b2[col];
#pragma unroll
            for (int rr = 0; rr < 4; ++rr) psum[rr] += (acc[nt][rr] + bb) * fw;
        }
#pragma unroll
        for (int rr = 0; rr < 4; ++rr)
#pragma unroll
            for (int off = 8; off > 0; off >>= 1)
                psum[rr] += __shfl_down(psum[rr], off, 64);
        float* gsum = reinterpret_cast<float*>(hlh);
        gsum[tid] = 0.f;  // tid 0..255 == graph ids
        __syncthreads();
        if (m == 0) {
#pragma unroll
            for (int rr = 0; rr < 4; ++rr) {
                int row = base + wv * 16 + quad * 4 + rr;
                if (row < NN) atomicAdd(&gsum[batch[row]], psum[rr]);
            }
        }
        __syncthreads();
        float v = gsum[tid];
        if (v != 0.f) unsafeAtomicAdd(&outp[tid], v);
        return;
    }

    // ---- epilogue: bias (+relu) -> LDS bf16, then coalesced stores ----
#pragma unroll
    for (int nt = 0; nt < 4; ++nt) {
        int col = nt * 16 + m;
        float bb = b2[col];
#pragma unroll
        for (int rr = 0; rr < 4; ++rr) {
            float v = acc[nt][rr] + bb;
            if (relu_out) v = fmaxf(v, 0.f);
            hlh[(wv * 16 + quad * 4 + rr) * 72 + col] = f2b(v);
        }
    }
    __syncthreads();
    for (int i = tid; i < 64 * 8; i += 256) {
        int row = i >> 3;
        int ch = i & 7;
        int orow = base + row;
        if (orow < NN) {
            uint4 v = *reinterpret_cast<const uint4*>(&hlh[row * 72 + ch * 8]);
            *reinterpret_cast<uint4*>(houtb + (size_t)orow * 64 + ch * 8) = v;
        }
    }
}

extern "C" void kernel_launch(void* const* d_in, const int* in_sizes, int n_in,
                              void* d_out, int out_size, void* d_ws, size_t ws_size,
                              hipStream_t stream) {
    const float* x = (const float*)d_in[0];
    const int* ei = (const int*)d_in[1];     // [2, E] flat
    const int* batch = (const int*)d_in[2];  // [N], sorted
    const float* w[3][4];
    for (int l = 0; l < 3; ++l)
        for (int i = 0; i < 4; ++i) w[l][i] = (const float*)d_in[3 + l * 4 + i];
    const float* fcw = (const float*)d_in[15];
    const float* fcb = (const float*)d_in[16];
    float* out = (float*)d_out;

    // workspace layout (~45 MB)
    int* pairs = (int*)d_ws;                               // NBKT*CAP ints (25.6 MB)
    unsigned short* Z = (unsigned short*)d_ws;             // bf16 z, aliases pairs
    unsigned short* H = (unsigned short*)((char*)d_ws + (size_t)NBKT * CAP * 4);  // 12.8 MB
    int* rowptr = (int*)(H + (size_t)NN * DD);             // N+1
    int* csr_src = rowptr + NN + 1;                        // NE (6.4 MB)
    int* gcnt = csr_src + NE;                              // NBKT
    unsigned short* wf = (unsigned short*)(gcnt + NBKT);   // 6*8192 bf16 (96 KB)

    // one-time prep: weights->split-bf16 frags, x->bf16, gcnt=0, out=fcb
    prep_k<<<7 + (NN * 16 + 255) / 256, 256, 0, stream>>>(
        w[0][0], w[0][2], w[1][0], w[1][2], w[2][0], w[2][2], wf, x, H, gcnt, fcb,
        out);

    // CSR build (pairs consumed by bfill before Z is first written)
    pscat_k<<<NEB, 256, 0, stream>>>(ei, gcnt, pairs);
    bfill_k<<<NBKT, 256, 0, stream>>>(pairs, gcnt, rowptr, csr_src);

    dim3 ggrid((NN + 31) / 32), mgrid((NN + 63) / 64);
    // L0
    gather_k<<<ggrid, 256, 0, stream>>>((const uint4*)H, (const float4*)x, rowptr,
                                        csr_src, (uint4*)Z);
    mlp_k<<<mgrid, 256, 0, stream>>>(Z, wf + 0 * 8192, w[0][1], wf + 1 * 8192,
                                     w[0][3], H, 1, 0, nullptr, nullptr, nullptr);
    // L1
    gather_k<<<ggrid, 256, 0, stream>>>((const uint4*)H, nullptr, rowptr, csr_src,
                                        (uint4*)Z);
    mlp_k<<<mgrid, 256, 0, stream>>>(Z, wf + 2 * 8192, w[1][1], wf + 3 * 8192,
                                     w[1][3], H, 1, 0, nullptr, nullptr, nullptr);
    // L2: fused pool + FC (no H write)
    gather_k<<<ggrid, 256, 0, stream>>>((const uint4*)H, nullptr, rowptr, csr_src,
                                        (uint4*)Z);
    mlp_k<<<mgrid, 256, 0, stream>>>(Z, wf + 4 * 8192, w[2][1], wf + 5 * 8192,
                                     w[2][3], nullptr, 0, 1, batch, fcw, out);
}

// Round 14
// 277.495 us; speedup vs baseline: 1.7180x; 1.1015x over previous
//
#include <hip/hip_runtime.h>

constexpr int NN = 100000;   // nodes (= 3125 * 32 exactly)
constexpr int NE = 1600000;  // edges
constexpr int DD = 64;       // channels
constexpr int NG = 256;      // graphs

constexpr int BKT_SHIFT = 8;                   // 256 nodes per bucket
constexpr int NBKT = (NN + 255) >> BKT_SHIFT;  // 391 buckets
constexpr int EPB = 4096;                      // edges per block (build kernels)
constexpr int NEB = (NE + EPB - 1) / EPB;      // 391 blocks
constexpr int CAP = 16384;                     // pair window per bucket (mean 4092)

using bf16x8 = __attribute__((ext_vector_type(8))) short;
using f32x4 = __attribute__((ext_vector_type(4))) float;

// ---------------------------------------------------------------------------
// bf16 helpers (manual, RNE)
// ---------------------------------------------------------------------------
__device__ __forceinline__ float b2f(unsigned short u) {
    union { unsigned int u; float f; } c;
    c.u = ((unsigned int)u) << 16;
    return c.f;
}
__device__ __forceinline__ unsigned short f2b(float f) {
    union { float f; unsigned int u; } c;
    c.f = f;
    unsigned int u = c.u + 0x7fff + ((c.u >> 16) & 1);
    return (unsigned short)(u >> 16);
}
__device__ __forceinline__ float lo16(unsigned int u) {
    union { unsigned int u; float f; } c;
    c.u = u << 16;
    return c.f;
}
__device__ __forceinline__ float hi16(unsigned int u) {
    union { unsigned int u; float f; } c;
    c.u = u & 0xffff0000u;
    return c.f;
}
__device__ __forceinline__ unsigned int pk(float a, float b) {
    return ((unsigned int)f2b(a)) | (((unsigned int)f2b(b)) << 16);
}

// ---------------------------------------------------------------------------
// prep_k: fused one-time prep.
//   blocks 0..5   : weight -> split bf16 (hi + residual lo), B-frag order
//   block  6      : out[g] = fcb; gcnt = 0
//   blocks 7..    : x (fp32) -> bf16
// ---------------------------------------------------------------------------
__global__ __launch_bounds__(256) void prep_k(const float* __restrict__ w0,
                                              const float* __restrict__ w1,
                                              const float* __restrict__ w2,
                                              const float* __restrict__ w3,
                                              const float* __restrict__ w4,
                                              const float* __restrict__ w5,
                                              unsigned short* __restrict__ wf,
                                              const float* __restrict__ x,
                                              unsigned short* __restrict__ xb,
                                              int* __restrict__ gcnt,
                                              const float* __restrict__ fcb,
                                              float* __restrict__ outp) {
    int bid = blockIdx.x;
    int tid = threadIdx.x;
    if (bid < 6) {
        const float* ws[6] = {w0, w1, w2, w3, w4, w5};
        const float* w = ws[bid];
        unsigned short* o = wf + bid * 8192;
        for (int i = tid; i < 4096; i += 256) {
            int j = i & 7;
            int quad = (i >> 3) & 3;
            int n = (i >> 5) & 63;
            int kb = i >> 11;
            int k = kb * 32 + quad * 8 + j;
            float wv = w[k * 64 + n];
            unsigned short hi = f2b(wv);
            o[i] = hi;
            o[i + 4096] = f2b(wv - b2f(hi));
        }
    } else if (bid == 6) {
        if (tid < NG) outp[tid] = fcb[0];
        for (int i = tid; i < NBKT; i += 256) gcnt[i] = 0;
    } else {
        int i = (bid - 7) * 256 + tid;
        if (i < NN * 16) {
            float4 v = reinterpret_cast<const float4*>(x)[i];
            ushort4 o;
            o.x = f2b(v.x); o.y = f2b(v.y); o.z = f2b(v.z); o.w = f2b(v.w);
            reinterpret_cast<ushort4*>(xb)[i] = o;
        }
    }
}

// ---------------------------------------------------------------------------
// pscat: edges -> bucket-major packed pairs (one global pass, LDS staged).
// pairs packed: src (17 bits) | local-dst (8 bits) << 17.
// ---------------------------------------------------------------------------
__global__ __launch_bounds__(256) void pscat_k(const int* __restrict__ ei,
                                               int* __restrict__ gcnt,
                                               int* __restrict__ pairs) {
    __shared__ int lc[NBKT];
    __shared__ int gb[NBKT];
    __shared__ int pe[EPB];
    __shared__ unsigned short pb[EPB];
    int tid = threadIdx.x;
    for (int i = tid; i < NBKT; i += 256) lc[i] = 0;
    __syncthreads();
    int base = blockIdx.x * EPB;
    int n = min(base + EPB, NE) - base;
    for (int t = tid; t < n; t += 256) {
        int src = ei[base + t];
        int dst = ei[NE + base + t];
        int b = dst >> BKT_SHIFT;
        pe[t] = src | ((dst & 255) << 17);
        pb[t] = (unsigned short)b;
        atomicAdd(&lc[b], 1);
    }
    __syncthreads();
    for (int i = tid; i < NBKT; i += 256) {
        int c = lc[i];
        gb[i] = c ? atomicAdd(&gcnt[i], c) : 0;
    }
    __syncthreads();
    for (int i = tid; i < NBKT; i += 256) lc[i] = 0;
    __syncthreads();
    for (int t = tid; t < n; t += 256) {
        int b = pb[t];
        int pos = gb[b] + atomicAdd(&lc[b], 1);
        if (pos < CAP) pairs[(size_t)b * CAP + pos] = pe[t];
    }
}

// ---------------------------------------------------------------------------
// bfill: bucket pairs -> rowptr + csr_src, block-local prefix over gcnt.
// ---------------------------------------------------------------------------
__global__ __launch_bounds__(256) void bfill_k(const int* __restrict__ pairs,
                                               const int* __restrict__ gcnt,
                                               int* __restrict__ rowptr,
                                               int* __restrict__ csr_src) {
    __shared__ int ldeg[256];
    __shared__ int sh[256];
    __shared__ int lcur[256];
    __shared__ int redsh[4];
    int b = blockIdx.x;
    int t = threadIdx.x;
    int part = 0;
    for (int i = t; i < NBKT; i += 256)
        if (i < b) part += min(gcnt[i], CAP);
#pragma unroll
    for (int off = 32; off > 0; off >>= 1) part += __shfl_down(part, off, 64);
    if ((t & 63) == 0) redsh[t >> 6] = part;
    ldeg[t] = 0;
    __syncthreads();
    int cbeg = redsh[0] + redsh[1] + redsh[2] + redsh[3];
    int pcnt = min(gcnt[b], CAP);
    const int* pw = pairs + (size_t)b * CAP;
    for (int i = t; i < pcnt; i += 256)
        atomicAdd(&ldeg[(pw[i] >> 17) & 255], 1);
    __syncthreads();
    int v = ldeg[t];
    sh[t] = v;
    __syncthreads();
    for (int off = 1; off < 256; off <<= 1) {
        int u = (t >= off) ? sh[t - off] : 0;
        __syncthreads();
        sh[t] += u;
        __syncthreads();
    }
    int lexcl = sh[t] - v;
    int node = (b << BKT_SHIFT) + t;
    if (node < NN) {
        rowptr[node] = cbeg + lexcl;
        if (node == NN - 1) rowptr[NN] = cbeg + lexcl + v;
    }
    lcur[t] = lexcl;
    __syncthreads();
    for (int i = t; i < pcnt; i += 256) {
        int p = pw[i];
        int pos = atomicAdd(&lcur[(p >> 17) & 255], 1);
        csr_src[cbeg + pos] = p & 0x1FFFF;
    }
}

// ---------------------------------------------------------------------------
// Fused GIN layer: gather (8 nodes/wave, round-10 structure, z -> LDS) +
// split-bf16 MFMA MLP on the 32-row tile. No global z. Reads Hin (neighbor
// rows + self), writes Hout (ping-pong: no same-buffer hazard).
// Wave roles in MLP: mt = wv>>1 (row half), nh = wv&1 (col half).
// LDS stride 72 shorts everywhere (bank-uniform for b128 frag access).
// ---------------------------------------------------------------------------
__global__ __launch_bounds__(256) void gin_k(
    const uint4* __restrict__ hb4,     // prev h (bf16): gather + self source
    const float4* __restrict__ selff,  // fp32 self (layer 0) or null
    const int* __restrict__ rowptr,
    const int* __restrict__ csr_src,
    const unsigned short* __restrict__ wf1, const float* __restrict__ b1,
    const unsigned short* __restrict__ wf2, const float* __restrict__ b2,
    unsigned short* __restrict__ houtb, int relu_out, int pool_mode,
    const int* __restrict__ batch, const float* __restrict__ fcw,
    float* __restrict__ outp) {
    __shared__ unsigned short zl[32 * 72];   // z tile (bf16)
    __shared__ unsigned short hlh[32 * 72];  // h1 hi
    __shared__ unsigned short hll[32 * 72];  // h1 lo
    int tid = threadIdx.x;
    int lane = tid & 63;
    int wv = tid >> 6;
    int base = blockIdx.x * 32;

    // ---- Phase A: gather + self -> zl (NN == 3125*32, all nodes valid) ----
    {
        int nl = lane >> 3;  // node slot within wave (0..7)
        int c = lane & 7;    // 16 B chunk within row (0..7)
        int r = wv * 8 + nl; // local row 0..31
        int node = base + r;
        int beg = rowptr[node];
        int deg = rowptr[node + 1] - beg;
        float a0 = 0, a1 = 0, a2 = 0, a3 = 0, a4 = 0, a5 = 0, a6 = 0, a7 = 0;
        int nb = (deg + 7) >> 3;
        int idx = (c < deg) ? csr_src[beg + c] : 0;
        int gbase = nl << 3;
        for (int b = 0; b < nb; ++b) {
            int nj = ((b + 1) << 3) + c;
            int nextIdx = (b + 1 < nb && nj < deg) ? csr_src[beg + nj] : 0;
            int cnt = min(8, deg - (b << 3));
            int s0 = __shfl(idx, gbase, 64);
            uint4 v0 = hb4[s0 * 8 + c];
            for (int e = 1; e < cnt; ++e) {
                int s1 = __shfl(idx, gbase + e, 64);
                uint4 v1 = hb4[s1 * 8 + c];  // issue before consuming v0
                a0 += lo16(v0.x); a1 += hi16(v0.x);
                a2 += lo16(v0.y); a3 += hi16(v0.y);
                a4 += lo16(v0.z); a5 += hi16(v0.z);
                a6 += lo16(v0.w); a7 += hi16(v0.w);
                v0 = v1;
            }
            a0 += lo16(v0.x); a1 += hi16(v0.x);
            a2 += lo16(v0.y); a3 += hi16(v0.y);
            a4 += lo16(v0.z); a5 += hi16(v0.z);
            a6 += lo16(v0.w); a7 += hi16(v0.w);
            idx = nextIdx;
        }
        if (selff) {
            float4 s0 = selff[(size_t)node * 16 + 2 * c];
            float4 s1 = selff[(size_t)node * 16 + 2 * c + 1];
            a0 += s0.x; a1 += s0.y; a2 += s0.z; a3 += s0.w;
            a4 += s1.x; a5 += s1.y; a6 += s1.z; a7 += s1.w;
        } else {
            uint4 sv = hb4[node * 8 + c];
            a0 += lo16(sv.x); a1 += hi16(sv.x);
            a2 += lo16(sv.y); a3 += hi16(sv.y);
            a4 += lo16(sv.z); a5 += hi16(sv.z);
            a6 += lo16(sv.w); a7 += hi16(sv.w);
        }
        uint4 o;
        o.x = pk(a0, a1); o.y = pk(a2, a3); o.z = pk(a4, a5); o.w = pk(a6, a7);
        *reinterpret_cast<uint4*>(&zl[r * 72 + c * 8]) = o;
    }
    __syncthreads();

    // ---- Phase B: MLP on the 32-row tile ----
    int m = lane & 15;
    int quad = lane >> 4;
    int mt = wv >> 1;  // row half (rows mt*16 + 0..15)
    int nh = wv & 1;   // col half (n-tiles nh*2, nh*2+1)
    int lrow = mt * 16 + m;

    bf16x8 a0 = *reinterpret_cast<const bf16x8*>(&zl[lrow * 72 + quad * 8]);
    bf16x8 a1 = *reinterpret_cast<const bf16x8*>(&zl[lrow * 72 + 32 + quad * 8]);
    const bf16x8* wh1 = reinterpret_cast<const bf16x8*>(wf1);
    const bf16x8* wl1 = reinterpret_cast<const bf16x8*>(wf1 + 4096);
    f32x4 acc[2];
#pragma unroll
    for (int nt2 = 0; nt2 < 2; ++nt2) {
        int n = (nh * 2 + nt2) * 16 + m;
        bf16x8 bh0 = wh1[(0 * 64 + n) * 4 + quad];
        bf16x8 bh1 = wh1[(1 * 64 + n) * 4 + quad];
        bf16x8 bl0 = wl1[(0 * 64 + n) * 4 + quad];
        bf16x8 bl1 = wl1[(1 * 64 + n) * 4 + quad];
        f32x4 c = {0.f, 0.f, 0.f, 0.f};
        c = __builtin_amdgcn_mfma_f32_16x16x32_bf16(a0, bh0, c, 0, 0, 0);
        c = __builtin_amdgcn_mfma_f32_16x16x32_bf16(a1, bh1, c, 0, 0, 0);
        c = __builtin_amdgcn_mfma_f32_16x16x32_bf16(a0, bl0, c, 0, 0, 0);
        c = __builtin_amdgcn_mfma_f32_16x16x32_bf16(a1, bl1, c, 0, 0, 0);
        acc[nt2] = c;
    }
    // h1 = ReLU(acc + b1) -> split bf16 into LDS (C-layout scatter)
#pragma unroll
    for (int nt2 = 0; nt2 < 2; ++nt2) {
        int col = (nh * 2 + nt2) * 16 + m;
        float bb = b1[col];
#pragma unroll
        for (int rr = 0; rr < 4; ++rr) {
            float v = fmaxf(acc[nt2][rr] + bb, 0.f);
            unsigned short hi = f2b(v);
            hlh[(mt * 16 + quad * 4 + rr) * 72 + col] = hi;
            hll[(mt * 16 + quad * 4 + rr) * 72 + col] = f2b(v - b2f(hi));
        }
    }
    __syncthreads();

    // GEMM2: A (hi+lo) from LDS
    bf16x8 ch0 = *reinterpret_cast<const bf16x8*>(&hlh[lrow * 72 + quad * 8]);
    bf16x8 ch1 = *reinterpret_cast<const bf16x8*>(&hlh[lrow * 72 + 32 + quad * 8]);
    bf16x8 cl0 = *reinterpret_cast<const bf16x8*>(&hll[lrow * 72 + quad * 8]);
    bf16x8 cl1 = *reinterpret_cast<const bf16x8*>(&hll[lrow * 72 + 32 + quad * 8]);
    const bf16x8* wh2 = reinterpret_cast<const bf16x8*>(wf2);
    const bf16x8* wl2 = reinterpret_cast<const bf16x8*>(wf2 + 4096);
#pragma unroll
    for (int nt2 = 0; nt2 < 2; ++nt2) {
        int n = (nh * 2 + nt2) * 16 + m;
        bf16x8 bh0 = wh2[(0 * 64 + n) * 4 + quad];
        bf16x8 bh1 = wh2[(1 * 64 + n) * 4 + quad];
        bf16x8 bl0 = wl2[(0 * 64 + n) * 4 + quad];
        bf16x8 bl1 = wl2[(1 * 64 + n) * 4 + quad];
        f32x4 c = {0.f, 0.f, 0.f, 0.f};
        c = __builtin_amdgcn_mfma_f32_16x16x32_bf16(ch0, bh0, c, 0, 0, 0);
        c = __builtin_amdgcn_mfma_f32_16x16x32_bf16(ch1, bh1, c, 0, 0, 0);
        c = __builtin_amdgcn_mfma_f32_16x16x32_bf16(ch0, bl0, c, 0, 0, 0);
        c = __builtin_amdgcn_mfma_f32_16x16x32_bf16(ch1, bl1, c, 0, 0, 0);
        c = __builtin_amdgcn_mfma_f32_16x16x32_bf16(cl0, bh0, c, 0, 0, 0);
        c = __builtin_amdgcn_mfma_f32_16x16x32_bf16(cl1, bh1, c, 0, 0, 0);
        acc[nt2] = c;
    }
    __syncthreads();  // all GEMM2 LDS reads done; hlh/hll reusable

    if (pool_mode) {
        // fused global_add_pool + FC
        float psum[4] = {0.f, 0.f, 0.f, 0.f};
#pragma unroll
        for (int nt2 = 0; nt2 < 2; ++nt2) {
            int col = (nh * 2 + nt2) * 16 + m;
            float fw = fcw[col];
            float bb = b2[col];
#pragma unroll
            for (int rr = 0; rr < 4; ++rr) psum[rr] += (acc[nt2][rr] + bb) * fw;
        }
#pragma unroll
        for (int rr = 0; rr < 4; ++rr)
#pragma unroll
            for (int off = 8; off > 0; off >>= 1)
                psum[rr] += __shfl_down(psum[rr], off, 64);
        float* gsum = reinterpret_cast<float*>(hlh);
        gsum[tid] = 0.f;  // tid 0..255 == graph ids
        __syncthreads();
        if (m == 0) {
#pragma unroll
            for (int rr = 0; rr < 4; ++rr) {
                int row = base + mt * 16 + quad * 4 + rr;
                atomicAdd(&gsum[batch[row]], psum[rr]);
            }
        }
        __syncthreads();
        float v = gsum[tid];
        if (v != 0.f) unsafeAtomicAdd(&outp[tid], v);
        return;
    }

    // epilogue: bias (+relu) -> LDS bf16, then coalesced stores
#pragma unroll
    for (int nt2 = 0; nt2 < 2; ++nt2) {
        int col = (nh * 2 + nt2) * 16 + m;
        float bb = b2[col];
#pragma unroll
        for (int rr = 0; rr < 4; ++rr) {
            float v = acc[nt2][rr] + bb;
            if (relu_out) v = fmaxf(v, 0.f);
            hlh[(mt * 16 + quad * 4 + rr) * 72 + col] = f2b(v);
        }
    }
    __syncthreads();
    {
        int row = tid >> 3;  // 0..31
        int ch = tid & 7;
        uint4 v = *reinterpret_cast<const uint4*>(&hlh[row * 72 + ch * 8]);
        *reinterpret_cast<uint4*>(houtb + (size_t)(base + row) * 64 + ch * 8) = v;
    }
}

extern "C" void kernel_launch(void* const* d_in, const int* in_sizes, int n_in,
                              void* d_out, int out_size, void* d_ws, size_t ws_size,
                              hipStream_t stream) {
    const float* x = (const float*)d_in[0];
    const int* ei = (const int*)d_in[1];     // [2, E] flat
    const int* batch = (const int*)d_in[2];  // [N], sorted
    const float* w[3][4];
    for (int l = 0; l < 3; ++l)
        for (int i = 0; i < 4; ++i) w[l][i] = (const float*)d_in[3 + l * 4 + i];
    const float* fcw = (const float*)d_in[15];
    const float* fcb = (const float*)d_in[16];
    float* out = (float*)d_out;

    // workspace layout (~58 MB)
    int* pairs = (int*)d_ws;                               // NBKT*CAP ints (25.6 MB)
    unsigned short* H1 = (unsigned short*)d_ws;            // bf16 h, aliases pairs
    unsigned short* H0 = (unsigned short*)((char*)d_ws + (size_t)NBKT * CAP * 4);  // 12.8 MB
    int* rowptr = (int*)(H0 + (size_t)NN * DD);            // N+1
    int* csr_src = rowptr + NN + 1;                        // NE (6.4 MB)
    int* gcnt = csr_src + NE;                              // NBKT
    unsigned short* wf = (unsigned short*)(gcnt + NBKT);   // 6*8192 bf16 (96 KB)

    // one-time prep: weights->split-bf16 frags, x->bf16 (H0), gcnt=0, out=fcb
    prep_k<<<7 + (NN * 16 + 255) / 256, 256, 0, stream>>>(
        w[0][0], w[0][2], w[1][0], w[1][2], w[2][0], w[2][2], wf, x, H0, gcnt, fcb,
        out);

    // CSR build (pairs consumed by bfill before H1 is first written)
    pscat_k<<<NEB, 256, 0, stream>>>(ei, gcnt, pairs);
    bfill_k<<<NBKT, 256, 0, stream>>>(pairs, gcnt, rowptr, csr_src);

    dim3 lgrid(NN / 32);
    // L0: read H0(=xb)+x, write H1
    gin_k<<<lgrid, 256, 0, stream>>>((const uint4*)H0, (const float4*)x, rowptr,
                                     csr_src, wf + 0 * 8192, w[0][1], wf + 1 * 8192,
                                     w[0][3], H1, 1, 0, nullptr, nullptr, nullptr);
    // L1: read H1, write H0
    gin_k<<<lgrid, 256, 0, stream>>>((const uint4*)H1, nullptr, rowptr, csr_src,
                                     wf + 2 * 8192, w[1][1], wf + 3 * 8192, w[1][3],
                                     H0, 1, 0, nullptr, nullptr, nullptr);
    // L2: read H0, fused pool + FC
    gin_k<<<lgrid, 256, 0, stream>>>((const uint4*)H0, nullptr, rowptr, csr_src,
                                     wf + 4 * 8192, w[2][1], wf + 5 * 8192, w[2][3],
                                     nullptr, 0, 1, batch, fcw, out);
}